// Round 1
// baseline (3421.109 us; speedup 1.0000x reference)
//
#include <hip/hip_runtime.h>
#include <hip/hip_bf16.h>

// ---------------- problem constants ----------------
#define NNODES 10000
#define EEDGES 160000
#define DIN    512
#define HD     512
#define OUTD   128
#define NLAYERS 3

#define ACT_NONE 0
#define ACT_RELU 1
#define ACT_ELU1 2

// ---------------- utility fills ----------------
__global__ void fill_f32(float* p, float v, int n) {
  int i = blockIdx.x * blockDim.x + threadIdx.x;
  if (i < n) p[i] = v;
}
__global__ void fill_i32(int* p, int v, int n) {
  int i = blockIdx.x * blockDim.x + threadIdx.x;
  if (i < n) p[i] = v;
}

// ---------------- edge-index width probe ----------------
// If the buffer is int64 (values < 2^31), every odd 32-bit word of the first
// E entries is 0. If it's int32, odd words are random node ids (~0 prob all 0).
__global__ void probe_i64_k(const void* ei, int* flag, int E_) {
  int i = blockIdx.x * blockDim.x + threadIdx.x;
  int idx = 2 * i + 1;
  if (i < E_) {
    if (((const int*)ei)[idx] != 0) atomicOr(flag, 1);
  }
}

__device__ inline void load_edge(const void* ei, int is_i32, int e, int E_, int& s, int& d) {
  if (is_i32) {
    s = ((const int*)ei)[e];
    d = ((const int*)ei)[E_ + e];
  } else {
    s = (int)((const long long*)ei)[e];
    d = (int)((const long long*)ei)[E_ + e];
  }
}

// ---------------- generic tiled f32 GEMM ----------------
// C[M,N] = act( (A[M,K] @ B[K,N] + bias?) + (BETA ? C : 0) ) with optional
// per-row scale applied before act. BM=BN=64, BK=16, 256 threads, 4x4/thread.
template<int ACT, int BETA, int HAS_BIAS, int HAS_SCALE>
__global__ __launch_bounds__(256) void gemm_k(
    const float* __restrict__ A, const float* __restrict__ B,
    const float* __restrict__ bias, const float* __restrict__ rowscale,
    float* __restrict__ C, int M, int N, int K)
{
  __shared__ float As[16][65];
  __shared__ float Bs[16][64];
  int tid = threadIdx.x;
  int tx = tid & 15, ty = tid >> 4;
  int row0 = blockIdx.y * 64, col0 = blockIdx.x * 64;
  int ar = tid >> 2, ac = (tid & 3) << 2;   // A tile: 64 rows x 16 cols
  int br = tid >> 4, bc = (tid & 15) << 2;  // B tile: 16 rows x 64 cols
  bool arow_ok = (row0 + ar) < M;
  const float* Ap = A + (long)(row0 + ar) * K + ac;
  const float* Bp = B + (long)br * N + col0 + bc;
  float acc[4][4] = {};
  for (int k0 = 0; k0 < K; k0 += 16) {
    float4 av = arow_ok ? *(const float4*)(Ap + k0)
                        : make_float4(0.f, 0.f, 0.f, 0.f);
    float4 bv = *(const float4*)(Bp + (long)k0 * N);
    As[ac + 0][ar] = av.x; As[ac + 1][ar] = av.y;
    As[ac + 2][ar] = av.z; As[ac + 3][ar] = av.w;
    *(float4*)&Bs[br][bc] = bv;
    __syncthreads();
#pragma unroll
    for (int kk = 0; kk < 16; ++kk) {
      float a[4], b[4];
#pragma unroll
      for (int i = 0; i < 4; i++) a[i] = As[kk][ty * 4 + i];
#pragma unroll
      for (int j = 0; j < 4; j++) b[j] = Bs[kk][tx * 4 + j];
#pragma unroll
      for (int i = 0; i < 4; i++)
#pragma unroll
        for (int j = 0; j < 4; j++)
          acc[i][j] = fmaf(a[i], b[j], acc[i][j]);
    }
    __syncthreads();
  }
#pragma unroll
  for (int i = 0; i < 4; i++) {
    int m = row0 + ty * 4 + i;
    if (m >= M) continue;
    float rs = HAS_SCALE ? rowscale[m] : 1.0f;
#pragma unroll
    for (int j = 0; j < 4; j++) {
      int n = col0 + tx * 4 + j;
      float v = acc[i][j];
      if (HAS_BIAS) v += bias[n];
      if (BETA) v += C[(long)m * N + n];
      if (HAS_SCALE) v *= rs;
      if (ACT == ACT_RELU) v = fmaxf(v, 0.f);
      if (ACT == ACT_ELU1) v = (v > 0.f) ? (v + 1.0f) : __expf(v);
      C[(long)m * N + n] = v;
    }
  }
}

// ---------------- kv = K^T @ V  (512x512, reduce over M rows) ----------------
// Split-K over gridDim.z chunks, atomicAdd epilogue. 32x32 tile, 2x2/thread.
__global__ __launch_bounds__(256) void ktv_k(
    const float* __restrict__ Kp, const float* __restrict__ Vp,
    float* __restrict__ KV, int M)
{
  __shared__ float ks[32][36];
  __shared__ float vs[32][36];
  int tid = threadIdx.x;
  int i0 = blockIdx.y * 32, j0 = blockIdx.x * 32;
  int lr = tid >> 3, lc = (tid & 7) << 2;
  int ty = tid >> 4, tx = tid & 15;
  int chunk = blockIdx.z;
  int nstart = chunk * 1250;
  int nend = min(nstart + 1250, M);
  float acc00 = 0, acc01 = 0, acc10 = 0, acc11 = 0;
  for (int n0 = nstart; n0 < nend; n0 += 32) {
    int n = n0 + lr;
    float4 a, b;
    if (n < nend) {
      a = *(const float4*)(Kp + (long)n * HD + i0 + lc);
      b = *(const float4*)(Vp + (long)n * HD + j0 + lc);
    } else {
      a = make_float4(0.f, 0.f, 0.f, 0.f);
      b = a;
    }
    ks[lr][lc + 0] = a.x; ks[lr][lc + 1] = a.y; ks[lr][lc + 2] = a.z; ks[lr][lc + 3] = a.w;
    vs[lr][lc + 0] = b.x; vs[lr][lc + 1] = b.y; vs[lr][lc + 2] = b.z; vs[lr][lc + 3] = b.w;
    __syncthreads();
#pragma unroll
    for (int nn = 0; nn < 32; ++nn) {
      float k0v = ks[nn][ty * 2 + 0], k1v = ks[nn][ty * 2 + 1];
      float v0v = vs[nn][tx * 2 + 0], v1v = vs[nn][tx * 2 + 1];
      acc00 = fmaf(k0v, v0v, acc00);
      acc01 = fmaf(k0v, v1v, acc01);
      acc10 = fmaf(k1v, v0v, acc10);
      acc11 = fmaf(k1v, v1v, acc11);
    }
    __syncthreads();
  }
  atomicAdd(&KV[(i0 + ty * 2 + 0) * HD + j0 + tx * 2 + 0], acc00);
  atomicAdd(&KV[(i0 + ty * 2 + 0) * HD + j0 + tx * 2 + 1], acc01);
  atomicAdd(&KV[(i0 + ty * 2 + 1) * HD + j0 + tx * 2 + 0], acc10);
  atomicAdd(&KV[(i0 + ty * 2 + 1) * HD + j0 + tx * 2 + 1], acc11);
}

// ---------------- ksum = column sum of K ----------------
__global__ void colsum_k(const float* __restrict__ Kp, float* __restrict__ out, int M) {
  int j = blockIdx.x * 256 + threadIdx.x;       // 2 blocks in x -> 512 cols
  int n0 = blockIdx.y * 250;
  int n1 = min(n0 + 250, M);
  float s = 0.f;
  for (int n = n0; n < n1; ++n) s += Kp[(long)n * HD + j];
  atomicAdd(&out[j], s);
}

// ---------------- z[n] = 1/max(dot(q[n,:], ksum), 1e-6), wave per row ------
__global__ __launch_bounds__(256) void z_k(
    const float* __restrict__ q, const float* __restrict__ ksum,
    float* __restrict__ z, int M)
{
  long gid = (long)blockIdx.x * blockDim.x + threadIdx.x;
  int row = (int)(gid >> 6);
  int lane = (int)(gid & 63);
  if (row >= M) return;
  const float* qr = q + (long)row * HD;
  float4 a = *(const float4*)(qr + lane * 4);
  float4 b = *(const float4*)(qr + 256 + lane * 4);
  float4 c = *(const float4*)(ksum + lane * 4);
  float4 d = *(const float4*)(ksum + 256 + lane * 4);
  float s = a.x * c.x + a.y * c.y + a.z * c.z + a.w * c.w
          + b.x * d.x + b.y * d.y + b.z * d.z + b.w * d.w;
#pragma unroll
  for (int o = 32; o > 0; o >>= 1) s += __shfl_down(s, o);
  if (lane == 0) z[row] = 1.0f / fmaxf(s, 1e-6f);
}

// ---------------- hg = LayerNorm(hg + h), one block per row ----------------
__global__ __launch_bounds__(256) void ln_res_k(float* __restrict__ hg,
                                                const float* __restrict__ h)
{
  int r = blockIdx.x;
  float* row = hg + (long)r * HD;
  const float* hr = h + (long)r * HD;
  int t = threadIdx.x;
  float a0 = row[t] + hr[t];
  float a1 = row[t + 256] + hr[t + 256];
  __shared__ float sb[4];
  float s = a0 + a1;
#pragma unroll
  for (int o = 32; o > 0; o >>= 1) s += __shfl_down(s, o);
  if ((t & 63) == 0) sb[t >> 6] = s;
  __syncthreads();
  float mean = (sb[0] + sb[1] + sb[2] + sb[3]) * (1.0f / HD);
  float d0 = a0 - mean, d1 = a1 - mean;
  float vsum = d0 * d0 + d1 * d1;
  __syncthreads();
#pragma unroll
  for (int o = 32; o > 0; o >>= 1) vsum += __shfl_down(vsum, o);
  if ((t & 63) == 0) sb[t >> 6] = vsum;
  __syncthreads();
  float var = (sb[0] + sb[1] + sb[2] + sb[3]) * (1.0f / HD);
  float inv = rsqrtf(var + 1e-5f);
  row[t] = d0 * inv;
  row[t + 256] = d1 * inv;
}

// ---------------- GCN pieces ----------------
__global__ void deg_count_k(const void* ei, const int* flag, float* deg, int E_) {
  int e = blockIdx.x * blockDim.x + threadIdx.x;
  if (e >= E_) return;
  int s, d;
  load_edge(ei, *flag, e, E_, s, d);
  atomicAdd(&deg[d], 1.0f);
}

__global__ void rsqrt_k(float* p, int n) {
  int i = blockIdx.x * blockDim.x + threadIdx.x;
  if (i < n) p[i] = rsqrtf(p[i]);
}

// self-loop term: out[n,:] = xw[n,:] * dis[n]^2
__global__ void gcn_self_k(const float* __restrict__ xw, const float* __restrict__ dis,
                           float* __restrict__ out)
{
  long i = (long)blockIdx.x * blockDim.x + threadIdx.x;  // over N*H/4
  if (i >= (long)NNODES * HD / 4) return;
  int n = (int)(i / (HD / 4));
  float dd = dis[n] * dis[n];
  float4 v = ((const float4*)xw)[i];
  v.x *= dd; v.y *= dd; v.z *= dd; v.w *= dd;
  ((float4*)out)[i] = v;
}

// wave per edge: out[dst,:] += xw[src,:] * dis[src]*dis[dst]
__global__ __launch_bounds__(256) void gcn_edge_k(
    const float* __restrict__ xw, const void* ei, const int* flag,
    const float* __restrict__ dis, float* __restrict__ out, int E_)
{
  long gid = (long)blockIdx.x * blockDim.x + threadIdx.x;
  int e = (int)(gid >> 6);
  int lane = (int)(gid & 63);
  if (e >= E_) return;
  int s, d;
  load_edge(ei, *flag, e, E_, s, d);
  float norm = dis[s] * dis[d];
  const float* xr = xw + (long)s * HD;
  float* orow = out + (long)d * HD;
  float4 a = *(const float4*)(xr + lane * 4);
  float4 b = *(const float4*)(xr + 256 + lane * 4);
  atomicAdd(&orow[lane * 4 + 0], a.x * norm);
  atomicAdd(&orow[lane * 4 + 1], a.y * norm);
  atomicAdd(&orow[lane * 4 + 2], a.z * norm);
  atomicAdd(&orow[lane * 4 + 3], a.w * norm);
  atomicAdd(&orow[256 + lane * 4 + 0], b.x * norm);
  atomicAdd(&orow[256 + lane * 4 + 1], b.y * norm);
  atomicAdd(&orow[256 + lane * 4 + 2], b.z * norm);
  atomicAdd(&orow[256 + lane * 4 + 3], b.w * norm);
}

__global__ void bias_relu_k(float* __restrict__ x, const float* __restrict__ bias) {
  long i = (long)blockIdx.x * blockDim.x + threadIdx.x;  // over N*H/4
  if (i >= (long)NNODES * HD / 4) return;
  int j4 = (int)(i % (HD / 4)) * 4;
  float4 v = ((float4*)x)[i];
  v.x = fmaxf(v.x + bias[j4 + 0], 0.f);
  v.y = fmaxf(v.y + bias[j4 + 1], 0.f);
  v.z = fmaxf(v.z + bias[j4 + 2], 0.f);
  v.w = fmaxf(v.w + bias[j4 + 3], 0.f);
  ((float4*)x)[i] = v;
}

// ---------------- host launcher ----------------
extern "C" void kernel_launch(void* const* d_in, const int* in_sizes, int n_in,
                              void* d_out, int out_size, void* d_ws, size_t ws_size,
                              hipStream_t stream) {
  const float* x     = (const float*)d_in[0];
  const void*  ei    = d_in[1];
  const float* W_in  = (const float*)d_in[2];
  const float* b_in  = (const float*)d_in[3];
  const float* Wq    = (const float*)d_in[4];
  const float* Wk    = (const float*)d_in[5];
  const float* Wv    = (const float*)d_in[6];
  const float* Wo    = (const float*)d_in[7];
  const float* bo    = (const float*)d_in[8];
  const float* W_gcn = (const float*)d_in[9];
  const float* b_gcn = (const float*)d_in[10];
  const float* W_mix = (const float*)d_in[11];
  const float* b_mix = (const float*)d_in[12];
  const float* W_cls = (const float*)d_in[13];
  const float* b_cls = (const float*)d_in[14];
  float* out = (float*)d_out;

  const long NH = (long)NNODES * HD;
  float* ws   = (float*)d_ws;
  float* x0   = ws;            // [N,H]
  float* hg   = x0 + NH;       // [N,H] running h_global
  float* q    = hg + NH;       // [N,H] (later: xw)
  float* kbuf = q + NH;        // [N,H] (later: t, h_graph)
  float* vbuf = kbuf + NH;     // [N,H] (later: h, h_mix)
  float* kv   = vbuf + NH;     // [H,H]
  float* ksum = kv + (long)HD * HD;  // [H]
  float* zbuf = ksum + HD;     // [N]
  float* deg  = zbuf + NNODES; // [N] -> becomes dis after rsqrt
  int*   flag = (int*)(deg + NNODES);
  // total ~103.6 MB of workspace

  dim3 blk(256);
  dim3 g_512(HD / 64, (NNODES + 63) / 64);    // (8, 157)
  dim3 g_128(OUTD / 64, (NNODES + 63) / 64);  // (2, 157)

  // x0 = relu(x @ W_in + b_in); hg = x0
  gemm_k<ACT_RELU, 0, 1, 0><<<g_512, blk, 0, stream>>>(x, W_in, b_in, nullptr, x0,
                                                       NNODES, HD, DIN);
  hipMemcpyAsync(hg, x0, NH * sizeof(float), hipMemcpyDeviceToDevice, stream);

  // edge-index dtype probe
  fill_i32<<<1, 1, 0, stream>>>(flag, 0, 1);
  probe_i64_k<<<(EEDGES + 255) / 256, 256, 0, stream>>>(ei, flag, EEDGES);

  for (int l = 0; l < NLAYERS; ++l) {
    const float* wq  = Wq + (long)l * HD * HD;
    const float* wk  = Wk + (long)l * HD * HD;
    const float* wv  = Wv + (long)l * HD * HD;
    const float* wo  = Wo + (long)l * HD * HD;
    const float* bol = bo + (long)l * HD;

    gemm_k<ACT_ELU1, 0, 0, 0><<<g_512, blk, 0, stream>>>(hg, wq, nullptr, nullptr, q,
                                                         NNODES, HD, HD);
    gemm_k<ACT_ELU1, 0, 0, 0><<<g_512, blk, 0, stream>>>(hg, wk, nullptr, nullptr, kbuf,
                                                         NNODES, HD, HD);
    gemm_k<ACT_NONE, 0, 0, 0><<<g_512, blk, 0, stream>>>(hg, wv, nullptr, nullptr, vbuf,
                                                         NNODES, HD, HD);
    // kv = k^T @ v  (split-K=8, atomic accumulate)
    fill_f32<<<(HD * HD + 255) / 256, 256, 0, stream>>>(kv, 0.f, HD * HD);
    dim3 gk(HD / 32, HD / 32, 8);
    ktv_k<<<gk, blk, 0, stream>>>(kbuf, vbuf, kv, NNODES);
    // ksum = colsum(k)
    fill_f32<<<(HD + 255) / 256, 256, 0, stream>>>(ksum, 0.f, HD);
    dim3 gc(2, 40);
    colsum_k<<<gc, blk, 0, stream>>>(kbuf, ksum, NNODES);
    // z
    z_k<<<(NNODES * 64 + 255) / 256, blk, 0, stream>>>(q, ksum, zbuf, NNODES);
    // t = (q @ kv) * z  -> kbuf (k is dead now)
    gemm_k<ACT_NONE, 0, 0, 1><<<g_512, blk, 0, stream>>>(q, kv, nullptr, zbuf, kbuf,
                                                         NNODES, HD, HD);
    // h = t @ wo + bo -> vbuf (v is dead now)
    gemm_k<ACT_NONE, 0, 1, 0><<<g_512, blk, 0, stream>>>(kbuf, wo, bol, nullptr, vbuf,
                                                         NNODES, HD, HD);
    // hg = LN(hg + h)
    ln_res_k<<<NNODES, blk, 0, stream>>>(hg, vbuf);
  }

  // ---- GCN branch ----
  // xw = x0 @ W_gcn -> q
  gemm_k<ACT_NONE, 0, 0, 0><<<g_512, blk, 0, stream>>>(x0, W_gcn, nullptr, nullptr, q,
                                                       NNODES, HD, HD);
  fill_f32<<<(NNODES + 255) / 256, 256, 0, stream>>>(deg, 1.0f, NNODES);
  deg_count_k<<<(EEDGES + 255) / 256, 256, 0, stream>>>(ei, flag, deg, EEDGES);
  rsqrt_k<<<(NNODES + 255) / 256, 256, 0, stream>>>(deg, NNODES);  // deg := dis
  // h_graph -> kbuf
  gcn_self_k<<<(int)((NH / 4 + 255) / 256), 256, 0, stream>>>(q, deg, kbuf);
  gcn_edge_k<<<(int)(((long)EEDGES * 64 + 255) / 256), 256, 0, stream>>>(q, ei, flag, deg,
                                                                         kbuf, EEDGES);
  bias_relu_k<<<(int)((NH / 4 + 255) / 256), 256, 0, stream>>>(kbuf, b_gcn);

  // ---- mix: relu([hg, h_graph] @ W_mix + b_mix) -> vbuf ----
  gemm_k<ACT_NONE, 0, 1, 0><<<g_512, blk, 0, stream>>>(hg, W_mix, b_mix, nullptr, vbuf,
                                                       NNODES, HD, HD);
  gemm_k<ACT_RELU, 1, 0, 0><<<g_512, blk, 0, stream>>>(kbuf, W_mix + (long)HD * HD,
                                                       nullptr, nullptr, vbuf,
                                                       NNODES, HD, HD);
  // ---- cls: out = h_mix @ W_cls + b_cls ----
  gemm_k<ACT_NONE, 0, 1, 0><<<g_128, blk, 0, stream>>>(vbuf, W_cls, b_cls, nullptr, out,
                                                       NNODES, OUTD, HD);
}

// Round 3
// 1052.456 us; speedup vs baseline: 3.2506x; 3.2506x over previous
//
#include <hip/hip_runtime.h>
#include <hip/hip_bf16.h>

// ================= problem constants =================
#define NNODES 10000
#define EEDGES 160000
#define HD     512
#define OUTD   128
#define NLAYERS 3
#define MP     10112           // NNODES padded to 79*128 (GEMM M-tiles, no load bounds checks)
#define KTP    10240           // transposed-K pad (multiple of 32 and of 640 split chunks)

#define ACT_NONE 0
#define ACT_RELU 1
#define ACT_ELU1 2

typedef __attribute__((ext_vector_type(8))) short bf16x8;   // 8 bf16 (4 VGPRs) - MFMA A/B frag
typedef __attribute__((ext_vector_type(4))) float f32x4;    // MFMA C/D frag

// ---- async global->LDS, 16B per lane (dest = wave-uniform base + lane*16) ----
__device__ __forceinline__ void gload16(const void* g, void* l) {
  __builtin_amdgcn_global_load_lds(
      (const __attribute__((address_space(1))) void*)g,
      (__attribute__((address_space(3))) void*)l, 16, 0, 0);
}

__device__ __forceinline__ void unp8(uint4 v, float* f) {
  const ushort* u = (const ushort*)&v;
#pragma unroll
  for (int j = 0; j < 8; ++j) f[j] = __uint_as_float(((unsigned)u[j]) << 16);
}

__device__ __forceinline__ ushort f2bu(float f) {
  __hip_bfloat16 h = __float2bfloat16(f);
  return *reinterpret_cast<ushort*>(&h);
}

// ================= utility fills =================
__global__ void fill_f32(float* p, float v, int n) {
  int i = blockIdx.x * blockDim.x + threadIdx.x;
  if (i < n) p[i] = v;
}
__global__ void fill_i32(int* p, int v, int n) {
  int i = blockIdx.x * blockDim.x + threadIdx.x;
  if (i < n) p[i] = v;
}

// ================= edge-index width probe =================
__global__ void probe_i64_k(const void* ei, int* flag, int E_) {
  int i = blockIdx.x * blockDim.x + threadIdx.x;
  if (i < E_) {
    if (((const int*)ei)[2 * i + 1] != 0) atomicOr(flag, 1);  // int32 layout detected
  }
}
__device__ inline void load_edge(const void* ei, int is_i32, int e, int E_, int& s, int& d) {
  if (is_i32) { s = ((const int*)ei)[e]; d = ((const int*)ei)[E_ + e]; }
  else { s = (int)((const long long*)ei)[e]; d = (int)((const long long*)ei)[E_ + e]; }
}

// ================= bf16 MFMA GEMM (m97 structure) =================
// C[M,N] = epi( A[M,lda]bf16 @ Bt[N,ldb]^T bf16 )   (Bt stored [N][K] row-major)
// 128x128 tile, BK=32, 256 thr = 4 waves (2x2), wave tile 64x64 = 4x4 16x16 frags.
// koff = blockIdx.z * Ksz supports split-K (ATOMIC=1 -> f32 atomicAdd epilogue).
template<int ACT, int HAS_BIAS, int HAS_SCALE, int HAS_BETA, int OUTF, int OUTB, int ATOMIC>
__global__ __launch_bounds__(256) void mgemm(
    const __hip_bfloat16* __restrict__ A, const __hip_bfloat16* __restrict__ Bt,
    const float* __restrict__ bias, const float* __restrict__ rowscale,
    const float* __restrict__ Cbeta, float* __restrict__ Cf,
    __hip_bfloat16* __restrict__ Cb, int M, int lda, int ldb, int ldc, int Ksz)
{
  __shared__ __align__(16) __hip_bfloat16 As[128 * 32];  // [row][32k], 64B rows, linear
  __shared__ __align__(16) __hip_bfloat16 Bs[128 * 32];
  int tid = threadIdx.x;
  int lane = tid & 63;
  int wave = tid >> 6;                 // 0..3
  int wm = wave >> 1, wn = wave & 1;   // 2x2 wave grid
  int row0 = blockIdx.y * 128;
  int col0 = blockIdx.x * 128;
  int koff = blockIdx.z * Ksz;
  int srow = lane >> 2;                // staging: row within 16-row chunk
  int sbyte = (lane & 3) * 16;         // byte offset within 64B row

  f32x4 acc[4][4];
#pragma unroll
  for (int i = 0; i < 4; ++i)
#pragma unroll
    for (int j = 0; j < 4; ++j) acc[i][j] = f32x4{0.f, 0.f, 0.f, 0.f};

  int r16 = lane & 15;
  int kg = (lane >> 4) * 16;           // byte offset of this lane's 8-bf16 k-group

  for (int k0 = koff; k0 < koff + Ksz; k0 += 32) {
    // stage: each wave 2 A-chunks + 2 B-chunks of 1024B (16 rows x 64B)
#pragma unroll
    for (int j = 0; j < 2; ++j) {
      int c = wave * 2 + j;
      const char* ga = (const char*)(A + (long)(row0 + c * 16 + srow) * lda + k0) + sbyte;
      gload16(ga, (char*)As + c * 1024);
      const char* gb = (const char*)(Bt + (long)(col0 + c * 16 + srow) * ldb + k0) + sbyte;
      gload16(gb, (char*)Bs + c * 1024);
    }
    __syncthreads();
    bf16x8 af[4], bfr[4];
#pragma unroll
    for (int i = 0; i < 4; ++i)
      af[i] = *(const bf16x8*)((const char*)As + (wm * 64 + i * 16 + r16) * 64 + kg);
#pragma unroll
    for (int i = 0; i < 4; ++i)
      bfr[i] = *(const bf16x8*)((const char*)Bs + (wn * 64 + i * 16 + r16) * 64 + kg);
#pragma unroll
    for (int i = 0; i < 4; ++i)
#pragma unroll
      for (int j = 0; j < 4; ++j)
        acc[i][j] = __builtin_amdgcn_mfma_f32_16x16x32_bf16(af[i], bfr[j], acc[i][j], 0, 0, 0);
    __syncthreads();
  }

  // epilogue: D col = lane&15, row = (lane>>4)*4 + r  [m89/m91-verified]
  int rg = (lane >> 4) * 4;
#pragma unroll
  for (int i = 0; i < 4; ++i) {
#pragma unroll
    for (int j = 0; j < 4; ++j) {
      int col = col0 + wn * 64 + j * 16 + r16;
#pragma unroll
      for (int r = 0; r < 4; ++r) {
        int row = row0 + wm * 64 + i * 16 + rg + r;
        if (row >= M) continue;
        float v = acc[i][j][r];
        if (ATOMIC) { atomicAdd(&Cf[(long)row * ldc + col], v); continue; }
        if (HAS_BIAS) v += bias[col];
        if (HAS_BETA) v += Cbeta[(long)row * ldc + col];
        if (HAS_SCALE) v *= rowscale[row];
        if (ACT == ACT_RELU) v = fmaxf(v, 0.f);
        if (ACT == ACT_ELU1) v = (v > 0.f) ? (v + 1.0f) : __expf(v);
        if (OUTF) Cf[(long)row * ldc + col] = v;
        if (OUTB) Cb[(long)row * ldc + col] = __float2bfloat16(v);
      }
    }
  }
}

// ================= weight transpose+cast f32->bf16 =================
// 16 matrices of [512][512] -> [512][512]^T packed at dst + z*262144
__global__ __launch_bounds__(256) void wtrans_k(
    const float* W_in, const float* Wq, const float* Wk, const float* Wv,
    const float* Wo, const float* W_gcn, const float* W_mix, __hip_bfloat16* dst)
{
  int z = blockIdx.z;
  const float* src;
  if (z == 0) src = W_in;
  else if (z <= 3) src = Wq + (long)(z - 1) * 262144;
  else if (z <= 6) src = Wk + (long)(z - 4) * 262144;
  else if (z <= 9) src = Wv + (long)(z - 7) * 262144;
  else if (z <= 12) src = Wo + (long)(z - 10) * 262144;
  else if (z == 13) src = W_gcn;
  else if (z == 14) src = W_mix;
  else src = W_mix + 262144;
  __hip_bfloat16* out = dst + (long)z * 262144;
  __shared__ float t[32][33];
  int r0 = blockIdx.y * 32, c0 = blockIdx.x * 32;
  int tx = threadIdx.x & 31, ty = threadIdx.x >> 5;
#pragma unroll
  for (int i = 0; i < 32; i += 8) t[ty + i][tx] = src[(long)(r0 + ty + i) * 512 + c0 + tx];
  __syncthreads();
#pragma unroll
  for (int i = 0; i < 32; i += 8)
    out[(long)(c0 + ty + i) * 512 + r0 + tx] = __float2bfloat16(t[tx][ty + i]);
}

// W_cls [512][128] -> [128][512]
__global__ __launch_bounds__(256) void wtrans_cls_k(const float* Wc, __hip_bfloat16* out) {
  __shared__ float t[32][33];
  int r0 = blockIdx.y * 32, c0 = blockIdx.x * 32;  // r over 512, c over 128
  int tx = threadIdx.x & 31, ty = threadIdx.x >> 5;
#pragma unroll
  for (int i = 0; i < 32; i += 8) t[ty + i][tx] = Wc[(long)(r0 + ty + i) * 128 + c0 + tx];
  __syncthreads();
#pragma unroll
  for (int i = 0; i < 32; i += 8)
    out[(long)(c0 + ty + i) * 512 + r0 + tx] = __float2bfloat16(t[tx][ty + i]);
}

// ================= cast x f32 -> bf16, zero-pad rows to MP =================
__global__ void castx_k(const float* __restrict__ x, __hip_bfloat16* __restrict__ xb) {
  long i = (long)blockIdx.x * 256 + threadIdx.x;     // 8 elems/thread
  long base = i * 8;
  if (base >= (long)MP * HD) return;
  int row = (int)(base >> 9);
  ushort o[8];
  if (row < NNODES) {
    float4 a = *(const float4*)(x + base);
    float4 b = *(const float4*)(x + base + 4);
    float f[8] = {a.x, a.y, a.z, a.w, b.x, b.y, b.z, b.w};
#pragma unroll
    for (int j = 0; j < 8; ++j) o[j] = f2bu(f[j]);
  } else {
#pragma unroll
    for (int j = 0; j < 8; ++j) o[j] = 0;
  }
  *(uint4*)((ushort*)xb + base) = *(const uint4*)o;
}

// ================= activation transpose bf16 [MP][512] -> [512][KTP], zero-pad =================
__global__ __launch_bounds__(256) void atrans_k(const __hip_bfloat16* __restrict__ src,
                                                __hip_bfloat16* __restrict__ dst) {
  __shared__ __hip_bfloat16 t[64][72];
  int n0 = blockIdx.x * 64, c0 = blockIdx.y * 64;
  int r = threadIdx.x >> 2;
  int cg = (threadIdx.x & 3) * 16;
  int n = n0 + r;
  uint4 a, b;
  if (n < NNODES) {
    const ushort* sp = (const ushort*)src + (long)n * HD + c0 + cg;
    a = *(const uint4*)sp;
    b = *(const uint4*)(sp + 8);
  } else { a = make_uint4(0, 0, 0, 0); b = a; }
  *(uint4*)&t[r][cg] = a;
  *(uint4*)&t[r][cg + 8] = b;
  __syncthreads();
  ushort ov[16];
#pragma unroll
  for (int j = 0; j < 16; ++j) ov[j] = ((const ushort*)&t[cg + j][0])[r];
  ushort* op = (ushort*)dst + (long)(c0 + r) * KTP + n0 + cg;
  *(uint4*)op = *(const uint4*)&ov[0];
  *(uint4*)(op + 8) = *(const uint4*)&ov[8];
}

// ================= ksum = column sum over valid rows =================
__global__ void colsum_k(const __hip_bfloat16* __restrict__ kb, float* __restrict__ ksum) {
  int j = blockIdx.x * 256 + threadIdx.x;           // grid.x = 2
  int n0 = blockIdx.y * 250, n1 = min(n0 + 250, NNODES);
  float s = 0.f;
  for (int n = n0; n < n1; ++n) s += __bfloat162float(kb[(long)n * HD + j]);
  atomicAdd(&ksum[j], s);
}

// ================= z[n] = 1/max(q.ksum, 1e-6) =================
__global__ __launch_bounds__(256) void z_k(const __hip_bfloat16* __restrict__ qb,
                                           const float* __restrict__ ksum, float* __restrict__ z) {
  long gid = (long)blockIdx.x * 256 + threadIdx.x;
  int row = (int)(gid >> 6), lane = (int)(gid & 63);
  if (row >= NNODES) return;
  uint4 qv = *(const uint4*)((const ushort*)qb + (long)row * HD + lane * 8);
  float f[8]; unp8(qv, f);
  const float* kk = ksum + lane * 8;
  float s = 0.f;
#pragma unroll
  for (int j = 0; j < 8; ++j) s += f[j] * kk[j];
#pragma unroll
  for (int o = 32; o > 0; o >>= 1) s += __shfl_down(s, o);
  if (lane == 0) z[row] = 1.0f / fmaxf(s, 1e-6f);
}

// ================= cast f32 -> bf16 =================
__global__ void cast_bf_k(const float* __restrict__ s, __hip_bfloat16* __restrict__ d, int n) {
  int i = blockIdx.x * 256 + threadIdx.x;
  if (i < n) d[i] = __float2bfloat16(s[i]);
}

// ================= hg = LN(hg + h) f32, also write bf16 copy =================
__global__ __launch_bounds__(256) void ln_res_k(float* __restrict__ hg, const float* __restrict__ h,
                                                __hip_bfloat16* __restrict__ hgb) {
  int r = blockIdx.x;
  float* row = hg + (long)r * HD;
  const float* hr = h + (long)r * HD;
  __hip_bfloat16* brow = hgb + (long)r * HD;
  int t = threadIdx.x;
  float a0 = row[t] + hr[t];
  float a1 = row[t + 256] + hr[t + 256];
  __shared__ float sb[4];
  float s = a0 + a1;
#pragma unroll
  for (int o = 32; o > 0; o >>= 1) s += __shfl_down(s, o);
  if ((t & 63) == 0) sb[t >> 6] = s;
  __syncthreads();
  float mean = (sb[0] + sb[1] + sb[2] + sb[3]) * (1.0f / HD);
  float d0 = a0 - mean, d1 = a1 - mean;
  float vs = d0 * d0 + d1 * d1;
  __syncthreads();
#pragma unroll
  for (int o = 32; o > 0; o >>= 1) vs += __shfl_down(vs, o);
  if ((t & 63) == 0) sb[t >> 6] = vs;
  __syncthreads();
  float var = (sb[0] + sb[1] + sb[2] + sb[3]) * (1.0f / HD);
  float inv = rsqrtf(var + 1e-5f);
  float o0 = d0 * inv, o1 = d1 * inv;
  row[t] = o0; row[t + 256] = o1;
  brow[t] = __float2bfloat16(o0); brow[t + 256] = __float2bfloat16(o1);
}

// ================= GCN: CSR build + gather =================
__global__ void cnt_k(const void* ei, const int* flag, int* cnt, int E_) {
  int e = blockIdx.x * blockDim.x + threadIdx.x;
  if (e >= E_) return;
  int s, d; load_edge(ei, *flag, e, E_, s, d);
  atomicAdd(&cnt[d], 1);
}
// one block: exclusive scan of cnt -> rowptr (+cursor copy), dis = rsqrt(cnt+1)
__global__ __launch_bounds__(256) void scan_k(const int* __restrict__ cnt, int* __restrict__ rowptr,
                                              int* __restrict__ cursor, float* __restrict__ dis) {
  __shared__ int ps[256];
  int t = threadIdx.x;
  int lo = t * 40, hi = min(lo + 40, NNODES);
  int s = 0;
  for (int i = lo; i < hi; ++i) s += cnt[i];
  ps[t] = s;
  __syncthreads();
  for (int o = 1; o < 256; o <<= 1) {
    int v = (t >= o) ? ps[t - o] : 0;
    __syncthreads();
    ps[t] += v;
    __syncthreads();
  }
  int run = (t == 0) ? 0 : ps[t - 1];
  for (int i = lo; i < hi; ++i) {
    rowptr[i] = run; cursor[i] = run;
    dis[i] = rsqrtf((float)cnt[i] + 1.0f);
    run += cnt[i];
  }
  if (t == 255) rowptr[NNODES] = run;
}
__global__ void csrfill_k(const void* ei, const int* flag, int* cursor, int* csr, int E_) {
  int e = blockIdx.x * blockDim.x + threadIdx.x;
  if (e >= E_) return;
  int s, d; load_edge(ei, *flag, e, E_, s, d);
  int pos = atomicAdd(&cursor[d], 1);
  csr[pos] = s;
}
// wave per dst row: h_graph[d] = relu( sum_src xw[src]*dis[s]*dis[d] + xw[d]*dis[d]^2 + b )
__global__ __launch_bounds__(256) void gcn_gather_k(
    const __hip_bfloat16* __restrict__ xwb, const int* __restrict__ rowptr,
    const int* __restrict__ csr, const float* __restrict__ dis,
    const float* __restrict__ bgcn, __hip_bfloat16* __restrict__ outb)
{
  int wid = (blockIdx.x * 256 + threadIdx.x) >> 6;
  int lane = threadIdx.x & 63;
  if (wid >= NNODES) return;
  int d = wid;
  float dd = dis[d];
  float acc[8], f[8];
  uint4 v = *(const uint4*)((const ushort*)xwb + (long)d * HD + lane * 8);
  unp8(v, f);
#pragma unroll
  for (int j = 0; j < 8; ++j) acc[j] = f[j] * dd * dd;
  int e0 = rowptr[d], e1 = rowptr[d + 1];
  for (int e = e0; e < e1; ++e) {
    int sN = csr[e];
    float w = dis[sN] * dd;
    uint4 xv = *(const uint4*)((const ushort*)xwb + (long)sN * HD + lane * 8);
    unp8(xv, f);
#pragma unroll
    for (int j = 0; j < 8; ++j) acc[j] = fmaf(f[j], w, acc[j]);
  }
  const float* bb = bgcn + lane * 8;
  ushort o[8];
#pragma unroll
  for (int j = 0; j < 8; ++j) o[j] = f2bu(fmaxf(acc[j] + bb[j], 0.f));
  *(uint4*)((ushort*)outb + (long)d * HD + lane * 8) = *(const uint4*)o;
}

// ================= host launcher =================
extern "C" void kernel_launch(void* const* d_in, const int* in_sizes, int n_in,
                              void* d_out, int out_size, void* d_ws, size_t ws_size,
                              hipStream_t stream) {
  const float* x     = (const float*)d_in[0];
  const void*  ei    = d_in[1];
  const float* W_in  = (const float*)d_in[2];
  const float* b_in  = (const float*)d_in[3];
  const float* Wq    = (const float*)d_in[4];
  const float* Wk    = (const float*)d_in[5];
  const float* Wv    = (const float*)d_in[6];
  const float* Wo    = (const float*)d_in[7];
  const float* bo    = (const float*)d_in[8];
  const float* W_gcn = (const float*)d_in[9];
  const float* b_gcn = (const float*)d_in[10];
  const float* W_mix = (const float*)d_in[11];
  const float* b_mix = (const float*)d_in[12];
  const float* W_cls = (const float*)d_in[13];
  const float* b_cls = (const float*)d_in[14];
  float* out = (float*)d_out;

  // ---- workspace layout (~102.8 MB) ----
  const long NHB = (long)MP * HD;          // 5,177,344 elems per bf16 act buffer
  char* p = (char*)d_ws;
  char* AG = p; p += 20971520;             // xb -> {kT,vT} -> hbuf/mixtmp (time-shared)
  __hip_bfloat16* x0b = (__hip_bfloat16*)p; p += NHB * 2;
  __hip_bfloat16* hgb = (__hip_bfloat16*)p; p += NHB * 2;
  __hip_bfloat16* qb  = (__hip_bfloat16*)p; p += NHB * 2;   // also xwb
  __hip_bfloat16* kb  = (__hip_bfloat16*)p; p += NHB * 2;   // also kvf, tb, hmixb
  __hip_bfloat16* vb  = (__hip_bfloat16*)p; p += NHB * 2;   // also kvb, hgraphb
  float* hg = (float*)p; p += (long)MP * HD * 4;
  __hip_bfloat16* WT  = (__hip_bfloat16*)p; p += 16L * 262144 * 2;
  __hip_bfloat16* WCT = (__hip_bfloat16*)p; p += 131072;
  float* ksum = (float*)p; p += 2048;
  float* zb   = (float*)p; p += (long)MP * 4;
  int* cnt    = (int*)p; p += 40000;
  int* rowptr = (int*)p; p += 40016;
  int* cursor = (int*)p; p += 40000;
  float* dis  = (float*)p; p += 40000;
  int* csr    = (int*)p; p += 640000;
  int* flag   = (int*)p; p += 4;

  __hip_bfloat16* xb = (__hip_bfloat16*)AG;
  __hip_bfloat16* kT = (__hip_bfloat16*)AG;
  __hip_bfloat16* vT = (__hip_bfloat16*)(AG + 10485760);
  float* hbuf   = (float*)AG;              // after kT/vT dead within a layer
  float* mixtmp = (float*)AG;              // after last layer
  float* kvf = (float*)kb;                 // kb dead after kT+colsum
  __hip_bfloat16* kvb = vb;                // vb dead after vT
  __hip_bfloat16* tb = kb;
  __hip_bfloat16* xwb = qb;
  __hip_bfloat16* hgraphb = vb;
  __hip_bfloat16* hmixb = kb;

  dim3 blk(256);
  dim3 gW(16, 16, 16), gWc(4, 16);
  dim3 gG(HD / 128, MP / 128);             // (4, 79) for N=512
  dim3 gCls(1, MP / 128);
  dim3 gKV(4, 4, 16);                      // split-K=16, 640 each over KTP
  dim3 gT(KTP / 64, HD / 64);              // (160, 8) transposes

  // ---- weights -> bf16 transposed ----
  wtrans_k<<<gW, blk, 0, stream>>>(W_in, Wq, Wk, Wv, Wo, W_gcn, W_mix, WT);
  wtrans_cls_k<<<gWc, blk, 0, stream>>>(W_cls, WCT);
  castx_k<<<(int)((NHB / 8 + 255) / 256), blk, 0, stream>>>(x, xb);

  // x0 = relu(x@W_in + b_in): f32 -> hg, bf16 -> x0b
  mgemm<ACT_RELU, 1, 0, 0, 1, 1, 0><<<gG, blk, 0, stream>>>(
      xb, WT, b_in, nullptr, nullptr, hg, x0b, MP, HD, HD, HD, HD);
  (void)hipMemcpyAsync(hgb, x0b, NHB * 2, hipMemcpyDeviceToDevice, stream);

  fill_i32<<<1, 1, 0, stream>>>(flag, 0, 1);
  probe_i64_k<<<(EEDGES + 255) / 256, 256, 0, stream>>>(ei, flag, EEDGES);

  for (int l = 0; l < NLAYERS; ++l) {
    const __hip_bfloat16* BtQ = WT + (long)(1 + l) * 262144;
    const __hip_bfloat16* BtK = WT + (long)(4 + l) * 262144;
    const __hip_bfloat16* BtV = WT + (long)(7 + l) * 262144;
    const __hip_bfloat16* BtO = WT + (long)(10 + l) * 262144;

    mgemm<ACT_ELU1, 0, 0, 0, 0, 1, 0><<<gG, blk, 0, stream>>>(
        hgb, BtQ, nullptr, nullptr, nullptr, nullptr, qb, MP, HD, HD, HD, HD);
    mgemm<ACT_ELU1, 0, 0, 0, 0, 1, 0><<<gG, blk, 0, stream>>>(
        hgb, BtK, nullptr, nullptr, nullptr, nullptr, kb, MP, HD, HD, HD, HD);
    mgemm<ACT_NONE, 0, 0, 0, 0, 1, 0><<<gG, blk, 0, stream>>>(
        hgb, BtV, nullptr, nullptr, nullptr, nullptr, vb, MP, HD, HD, HD, HD);

    atrans_k<<<gT, blk, 0, stream>>>(kb, kT);
    atrans_k<<<gT, blk, 0, stream>>>(vb, vT);
    fill_f32<<<2, 256, 0, stream>>>(ksum, 0.f, HD);
    colsum_k<<<dim3(2, 40), blk, 0, stream>>>(kb, ksum);

    // kvT[j][i] = sum_n v[n][j] k[n][i]  (A=vT, Bt=kT, K=10240 zero-padded)
    fill_f32<<<1024, 256, 0, stream>>>(kvf, 0.f, HD * HD);
    mgemm<ACT_NONE, 0, 0, 0, 0, 0, 1><<<gKV, blk, 0, stream>>>(
        vT, kT, nullptr, nullptr, nullptr, kvf, nullptr, HD, KTP, KTP, HD, 640);
    cast_bf_k<<<1024, 256, 0, stream>>>(kvf, kvb, HD * HD);

    z_k<<<2500, blk, 0, stream>>>(qb, ksum, zb);
    // t = (q @ kv) * z   (Bt = kvT bf16)
    mgemm<ACT_NONE, 0, 1, 0, 0, 1, 0><<<gG, blk, 0, stream>>>(
        qb, kvb, nullptr, zb, nullptr, nullptr, tb, MP, HD, HD, HD, HD);
    // h = t @ Wo + bo -> f32 hbuf (kT/vT dead now)
    mgemm<ACT_NONE, 1, 0, 0, 1, 0, 0><<<gG, blk, 0, stream>>>(
        tb, BtO, bo + (long)l * HD, nullptr, nullptr, hbuf, nullptr, MP, HD, HD, HD, HD);
    ln_res_k<<<NNODES, blk, 0, stream>>>(hg, hbuf, hgb);
  }

  // ---- GCN branch ----
  mgemm<ACT_NONE, 0, 0, 0, 0, 1, 0><<<gG, blk, 0, stream>>>(
      x0b, WT + 13L * 262144, nullptr, nullptr, nullptr, nullptr, xwb, MP, HD, HD, HD, HD);
  fill_i32<<<40, 256, 0, stream>>>(cnt, 0, NNODES);
  cnt_k<<<(EEDGES + 255) / 256, 256, 0, stream>>>(ei, flag, cnt, EEDGES);
  scan_k<<<1, 256, 0, stream>>>(cnt, rowptr, cursor, dis);
  csrfill_k<<<(EEDGES + 255) / 256, 256, 0, stream>>>(ei, flag, cursor, csr, EEDGES);
  gcn_gather_k<<<2500, blk, 0, stream>>>(xwb, rowptr, csr, dis, b_gcn, hgraphb);

  // ---- mix + cls ----
  mgemm<ACT_NONE, 1, 0, 0, 1, 0, 0><<<gG, blk, 0, stream>>>(
      hgb, WT + 14L * 262144, b_mix, nullptr, nullptr, mixtmp, nullptr, MP, HD, HD, HD, HD);
  mgemm<ACT_RELU, 0, 0, 1, 0, 1, 0><<<gG, blk, 0, stream>>>(
      hgraphb, WT + 15L * 262144, nullptr, nullptr, mixtmp, nullptr, hmixb, MP, HD, HD, HD, HD);
  mgemm<ACT_NONE, 1, 0, 0, 1, 0, 0><<<gCls, blk, 0, stream>>>(
      hmixb, WCT, b_cls, nullptr, nullptr, out, nullptr, NNODES, HD, HD, OUTD, HD);
}

// Round 5
// 765.938 us; speedup vs baseline: 4.4666x; 1.3741x over previous
//
#include <hip/hip_runtime.h>
#include <hip/hip_bf16.h>

// ================= problem constants =================
#define NNODES 10000
#define EEDGES 160000
#define HD     512
#define OUTD   128
#define NLAYERS 3
#define MP     10112           // NNODES padded to 79*128
#define KTP    10240           // transposed-layout K pad (mult of 32, 16*640)

#define ACT_NONE 0
#define ACT_RELU 1
#define ACT_ELU1 2

typedef __attribute__((ext_vector_type(8))) short bf16x8;
typedef __attribute__((ext_vector_type(4))) float f32x4;

__device__ __forceinline__ void gload16(const void* g, void* l) {
  __builtin_amdgcn_global_load_lds(
      (const __attribute__((address_space(1))) void*)g,
      (__attribute__((address_space(3))) void*)l, 16, 0, 0);
}

__device__ __forceinline__ void unp8(uint4 v, float* f) {
  const ushort* u = (const ushort*)&v;
#pragma unroll
  for (int j = 0; j < 8; ++j) f[j] = __uint_as_float(((unsigned)u[j]) << 16);
}

__device__ __forceinline__ ushort f2bu(float f) {
  __hip_bfloat16 h = __float2bfloat16(f);
  return *reinterpret_cast<ushort*>(&h);
}

__device__ __forceinline__ float elu1f(float v) {
  return (v > 0.f) ? (v + 1.0f) : __expf(v);
}

// ================= utility fills =================
__global__ void fill_f32(float* p, float v, int n) {
  int i = blockIdx.x * blockDim.x + threadIdx.x;
  if (i < n) p[i] = v;
}
__global__ void fill_i32(int* p, int v, int n) {
  int i = blockIdx.x * blockDim.x + threadIdx.x;
  if (i < n) p[i] = v;
}

// ================= edge-index width probe =================
__global__ void probe_i64_k(const void* ei, int* flag, int E_) {
  int i = blockIdx.x * blockDim.x + threadIdx.x;
  if (i < E_) {
    if (((const int*)ei)[2 * i + 1] != 0) atomicOr(flag, 1);  // int32 layout detected
  }
}
__device__ inline void load_edge(const void* ei, int is_i32, int e, int E_, int& s, int& d) {
  if (is_i32) { s = ((const int*)ei)[e]; d = ((const int*)ei)[E_ + e]; }
  else { s = (int)((const long long*)ei)[e]; d = (int)((const long long*)ei)[E_ + e]; }
}

// ================= bf16 MFMA GEMM (m97 structure) =================
// C = epi(A[M,lda] @ Bt[N,ldb]^T), Bt row-major [N][K].
// 128x128 tile, BK=32, 4 waves (2x2), wave tile 64x64.
// TQKV: N=1536 fused q/k/v epilogue -> qb (elu1), kT (elu1, transposed), vT (transposed).
template<int ACT, int HAS_BIAS, int HAS_SCALE, int OUTF, int OUTB, int ATOMIC, int TQKV>
__global__ __launch_bounds__(256) void mgemm(
    const __hip_bfloat16* __restrict__ A, const __hip_bfloat16* __restrict__ Bt,
    const float* __restrict__ bias, const float* __restrict__ rowscale,
    float* __restrict__ Cf, __hip_bfloat16* __restrict__ Cb,
    __hip_bfloat16* __restrict__ kTp, __hip_bfloat16* __restrict__ vTp,
    int M, int lda, int ldb, int ldc, int ldcb, int Ksz)
{
  __shared__ __align__(16) __hip_bfloat16 As[128 * 32];
  __shared__ __align__(16) __hip_bfloat16 Bs[128 * 32];
  int tid = threadIdx.x;
  int lane = tid & 63;
  int wave = tid >> 6;
  int wm = wave >> 1, wn = wave & 1;
  int row0 = blockIdx.y * 128;
  int col0 = blockIdx.x * 128;
  int koff = blockIdx.z * Ksz;
  int srow = lane >> 2;
  int sbyte = (lane & 3) * 16;

  f32x4 acc[4][4];
#pragma unroll
  for (int i = 0; i < 4; ++i)
#pragma unroll
    for (int j = 0; j < 4; ++j) acc[i][j] = f32x4{0.f, 0.f, 0.f, 0.f};

  int r16 = lane & 15;
  int kg = (lane >> 4) * 16;

  for (int k0 = koff; k0 < koff + Ksz; k0 += 32) {
#pragma unroll
    for (int j = 0; j < 2; ++j) {
      int c = wave * 2 + j;
      const char* ga = (const char*)(A + (long)(row0 + c * 16 + srow) * lda + k0) + sbyte;
      gload16(ga, (char*)As + c * 1024);
      const char* gb = (const char*)(Bt + (long)(col0 + c * 16 + srow) * ldb + k0) + sbyte;
      gload16(gb, (char*)Bs + c * 1024);
    }
    __syncthreads();
    bf16x8 af[4], bfr[4];
#pragma unroll
    for (int i = 0; i < 4; ++i)
      af[i] = *(const bf16x8*)((const char*)As + (wm * 64 + i * 16 + r16) * 64 + kg);
#pragma unroll
    for (int i = 0; i < 4; ++i)
      bfr[i] = *(const bf16x8*)((const char*)Bs + (wn * 64 + i * 16 + r16) * 64 + kg);
#pragma unroll
    for (int i = 0; i < 4; ++i)
#pragma unroll
      for (int j = 0; j < 4; ++j)
        acc[i][j] = __builtin_amdgcn_mfma_f32_16x16x32_bf16(af[i], bfr[j], acc[i][j], 0, 0, 0);
    __syncthreads();
  }

  // D frag: col = lane&15, row = (lane>>4)*4 + r  [m89/m91-verified]
  int rg = (lane >> 4) * 4;
  if (TQKV) {
    // col groups: 0:q(elu1)->Cb[row][c] ld ldcb; 1:k(elu1)->kT[c][row]; 2:v->vT[c][row]
    int colg = col0 + wn * 64;          // group uniform per block (128-tile inside 512-group)
    int g = colg >> 9;
#pragma unroll
    for (int i = 0; i < 4; ++i) {
      int rowbase = row0 + wm * 64 + i * 16 + rg;
      if (rowbase >= NNODES) continue;   // NNODES%4==0: quad-level skip exact
#pragma unroll
      for (int j = 0; j < 4; ++j) {
        int col = colg + j * 16 + r16;
        int c = col & 511;
        if (g == 0) {
#pragma unroll
          for (int r = 0; r < 4; ++r)
            Cb[(long)(rowbase + r) * ldcb + c] = __float2bfloat16(elu1f(acc[i][j][r]));
        } else {
          ushort4 o;
          o.x = f2bu(g == 1 ? elu1f(acc[i][j][0]) : acc[i][j][0]);
          o.y = f2bu(g == 1 ? elu1f(acc[i][j][1]) : acc[i][j][1]);
          o.z = f2bu(g == 1 ? elu1f(acc[i][j][2]) : acc[i][j][2]);
          o.w = f2bu(g == 1 ? elu1f(acc[i][j][3]) : acc[i][j][3]);
          ushort* T = (ushort*)(g == 1 ? kTp : vTp);
          *(ushort4*)(T + (long)c * KTP + rowbase) = o;
        }
      }
    }
    return;
  }
#pragma unroll
  for (int i = 0; i < 4; ++i) {
#pragma unroll
    for (int j = 0; j < 4; ++j) {
      int col = col0 + wn * 64 + j * 16 + r16;
#pragma unroll
      for (int r = 0; r < 4; ++r) {
        int row = row0 + wm * 64 + i * 16 + rg + r;
        if (row >= M) continue;
        float v = acc[i][j][r];
        if (ATOMIC) { atomicAdd(&Cf[(long)row * ldc + col], v); continue; }
        if (HAS_BIAS) v += bias[col];
        if (HAS_SCALE) v *= rowscale[row];
        if (ACT == ACT_RELU) v = fmaxf(v, 0.f);
        if (ACT == ACT_ELU1) v = elu1f(v);
        if (OUTF) Cf[(long)row * ldc + col] = v;
        if (OUTB) Cb[(long)row * ldcb + col] = __float2bfloat16(v);
      }
    }
  }
}

// ================= weight transpose+cast f32->bf16 =================
// z=0: W_in; z=1..9: layer l=(z-1)/3, {Wq,Wk,Wv}[(z-1)%3] -> WT slot z (per-layer qkv fused);
// z=10..12: Wo_l; z=13: W_gcn; z=14/15: W_mix halves -> WMT [512][1024].
__global__ __launch_bounds__(256) void wtrans_k(
    const float* W_in, const float* Wq, const float* Wk, const float* Wv,
    const float* Wo, const float* W_gcn, const float* W_mix,
    __hip_bfloat16* WT, __hip_bfloat16* WMT)
{
  int z = blockIdx.z;
  const float* src;
  __hip_bfloat16* out;
  int ldout = 512, koff = 0;
  if (z == 0) { src = W_in; out = WT; }
  else if (z <= 9) {
    int l = (z - 1) / 3, w = (z - 1) % 3;
    src = (w == 0 ? Wq : w == 1 ? Wk : Wv) + (long)l * 262144;
    out = WT + (long)z * 262144;
  } else if (z <= 12) { src = Wo + (long)(z - 10) * 262144; out = WT + (long)z * 262144; }
  else if (z == 13) { src = W_gcn; out = WT + 13L * 262144; }
  else { src = W_mix + (long)(z - 14) * 262144; out = WMT; ldout = 1024; koff = (z - 14) * 512; }
  __shared__ float t[32][33];
  int r0 = blockIdx.y * 32, c0 = blockIdx.x * 32;
  int tx = threadIdx.x & 31, ty = threadIdx.x >> 5;
#pragma unroll
  for (int i = 0; i < 32; i += 8) t[ty + i][tx] = src[(long)(r0 + ty + i) * 512 + c0 + tx];
  __syncthreads();
#pragma unroll
  for (int i = 0; i < 32; i += 8)
    out[(long)(c0 + ty + i) * ldout + koff + r0 + tx] = __float2bfloat16(t[tx][ty + i]);
}

// W_cls [512][128] -> WCT [128][512]
__global__ __launch_bounds__(256) void wtrans_cls_k(const float* Wc, __hip_bfloat16* out) {
  __shared__ float t[32][33];
  int r0 = blockIdx.y * 32, c0 = blockIdx.x * 32;
  int tx = threadIdx.x & 31, ty = threadIdx.x >> 5;
#pragma unroll
  for (int i = 0; i < 32; i += 8) t[ty + i][tx] = Wc[(long)(r0 + ty + i) * 128 + c0 + tx];
  __syncthreads();
#pragma unroll
  for (int i = 0; i < 32; i += 8)
    out[(long)(c0 + ty + i) * 512 + r0 + tx] = __float2bfloat16(t[tx][ty + i]);
}

// ================= cast x f32 -> bf16, zero-pad rows to MP =================
__global__ void castx_k(const float* __restrict__ x, __hip_bfloat16* __restrict__ xb) {
  long i = (long)blockIdx.x * 256 + threadIdx.x;
  long base = i * 8;
  if (base >= (long)MP * HD) return;
  int row = (int)(base >> 9);
  ushort o[8];
  if (row < NNODES) {
    float4 a = *(const float4*)(x + base);
    float4 b = *(const float4*)(x + base + 4);
    float f[8] = {a.x, a.y, a.z, a.w, b.x, b.y, b.z, b.w};
#pragma unroll
    for (int j = 0; j < 8; ++j) o[j] = f2bu(f[j]);
  } else {
#pragma unroll
    for (int j = 0; j < 8; ++j) o[j] = 0;
  }
  *(uint4*)((ushort*)xb + base) = *(const uint4*)o;
}

// ====== pad-zero kT/vT cols [10000,10240) + ksum[i] = rowsum(kT[i][0:10000]) ======
__global__ __launch_bounds__(256) void pzcs_k(__hip_bfloat16* kT, __hip_bfloat16* vT,
                                              float* __restrict__ ksum) {
  int i = (blockIdx.x * 256 + threadIdx.x) >> 6;   // 512 rows, grid 128
  int lane = threadIdx.x & 63;
  ushort* kr = (ushort*)kT + (long)i * KTP;
  ushort* vr = (ushort*)vT + (long)i * KTP;
  if (lane < 60) {
    ushort4 z4 = {0, 0, 0, 0};
    *(ushort4*)(kr + NNODES + lane * 4) = z4;
    *(ushort4*)(vr + NNODES + lane * 4) = z4;
  }
  float s = 0.f;
  for (int off = lane * 8; off < NNODES; off += 512) {
    uint4 v = *(const uint4*)(kr + off);
    float f[8]; unp8(v, f);
#pragma unroll
    for (int j = 0; j < 8; ++j) s += f[j];
  }
#pragma unroll
  for (int o = 32; o > 0; o >>= 1) s += __shfl_down(s, o);
  if (lane == 0) ksum[i] = s;
}

// ================= z[n] = 1/max(q.ksum, 1e-6) =================
__global__ __launch_bounds__(256) void z_k(const __hip_bfloat16* __restrict__ qb,
                                           const float* __restrict__ ksum, float* __restrict__ z) {
  long gid = (long)blockIdx.x * 256 + threadIdx.x;
  int row = (int)(gid >> 6), lane = (int)(gid & 63);
  if (row >= NNODES) return;
  uint4 qv = *(const uint4*)((const ushort*)qb + (long)row * HD + lane * 8);
  float f[8]; unp8(qv, f);
  const float* kk = ksum + lane * 8;
  float s = 0.f;
#pragma unroll
  for (int j = 0; j < 8; ++j) s += f[j] * kk[j];
#pragma unroll
  for (int o = 32; o > 0; o >>= 1) s += __shfl_down(s, o);
  if (lane == 0) z[row] = 1.0f / fmaxf(s, 1e-6f);
}

// ================= cast f32 -> bf16 (8/thread) =================
__global__ void cast8_k(const float* __restrict__ s, __hip_bfloat16* __restrict__ d, int n8) {
  int i = blockIdx.x * 256 + threadIdx.x;
  if (i >= n8) return;
  float4 a = ((const float4*)s)[2 * i], b = ((const float4*)s)[2 * i + 1];
  float f[8] = {a.x, a.y, a.z, a.w, b.x, b.y, b.z, b.w};
  ushort o[8];
#pragma unroll
  for (int j = 0; j < 8; ++j) o[j] = f2bu(f[j]);
  *(uint4*)((ushort*)d + (long)i * 8) = *(const uint4*)o;
}

// ====== hg = LN(hg + h); f32 -> hg, bf16 -> hgcat[:,0:512] (ld 1024). wave/row ======
__global__ __launch_bounds__(256) void ln_res_k(float* __restrict__ hg, const float* __restrict__ h,
                                                __hip_bfloat16* __restrict__ hgcat) {
  int wid = (blockIdx.x * 256 + threadIdx.x) >> 6;
  int lane = threadIdx.x & 63;
  if (wid >= NNODES) return;
  float* row = hg + (long)wid * HD + lane * 8;
  const float* hr = h + (long)wid * HD + lane * 8;
  float4 p0 = *(const float4*)row, p1 = *(const float4*)(row + 4);
  float4 q0 = *(const float4*)hr, q1 = *(const float4*)(hr + 4);
  float a[8] = {p0.x + q0.x, p0.y + q0.y, p0.z + q0.z, p0.w + q0.w,
                p1.x + q1.x, p1.y + q1.y, p1.z + q1.z, p1.w + q1.w};
  float s = 0.f;
#pragma unroll
  for (int j = 0; j < 8; ++j) s += a[j];
#pragma unroll
  for (int o = 1; o < 64; o <<= 1) s += __shfl_xor(s, o);
  float mean = s * (1.0f / HD);
  float vs = 0.f;
#pragma unroll
  for (int j = 0; j < 8; ++j) { a[j] -= mean; vs += a[j] * a[j]; }
#pragma unroll
  for (int o = 1; o < 64; o <<= 1) vs += __shfl_xor(vs, o);
  float inv = rsqrtf(vs * (1.0f / HD) + 1e-5f);
  ushort ob[8];
#pragma unroll
  for (int j = 0; j < 8; ++j) { a[j] *= inv; ob[j] = f2bu(a[j]); }
  *(float4*)row = make_float4(a[0], a[1], a[2], a[3]);
  *(float4*)(row + 4) = make_float4(a[4], a[5], a[6], a[7]);
  *(uint4*)((ushort*)hgcat + (long)wid * 1024 + lane * 8) = *(const uint4*)ob;
}

// ================= GCN: CSR build + gather =================
__global__ void cnt_k(const void* ei, const int* flag, int* cnt, int E_) {
  int e = blockIdx.x * blockDim.x + threadIdx.x;
  if (e >= E_) return;
  int s, d; load_edge(ei, *flag, e, E_, s, d);
  atomicAdd(&cnt[d], 1);
}
__global__ __launch_bounds__(256) void scan_k(const int* __restrict__ cnt, int* __restrict__ rowptr,
                                              int* __restrict__ cursor, float* __restrict__ dis) {
  __shared__ int ps[256];
  int t = threadIdx.x;
  int lo = t * 40, hi = min(lo + 40, NNODES);
  int s = 0;
  for (int i = lo; i < hi; ++i) s += cnt[i];
  ps[t] = s;
  __syncthreads();
  for (int o = 1; o < 256; o <<= 1) {
    int v = (t >= o) ? ps[t - o] : 0;
    __syncthreads();
    ps[t] += v;
    __syncthreads();
  }
  int run = (t == 0) ? 0 : ps[t - 1];
  for (int i = lo; i < hi; ++i) {
    rowptr[i] = run; cursor[i] = run;
    dis[i] = rsqrtf((float)cnt[i] + 1.0f);
    run += cnt[i];
  }
  if (t == 255) rowptr[NNODES] = run;
}
__global__ void csrfill_k(const void* ei, const int* flag, int* cursor, int* csr, int E_) {
  int e = blockIdx.x * blockDim.x + threadIdx.x;
  if (e >= E_) return;
  int s, d; load_edge(ei, *flag, e, E_, s, d);
  int pos = atomicAdd(&cursor[d], 1);
  csr[pos] = s;
}
// wave per dst: h_graph[d] = relu(sum_src xw[src]*dis[s]*dis[d] + xw[d]*dis[d]^2 + b)
// writes bf16 into hgcat[:,512:1024] (ld 1024)
__global__ __launch_bounds__(256) void gcn_gather_k(
    const __hip_bfloat16* __restrict__ xwb, const int* __restrict__ rowptr,
    const int* __restrict__ csr, const float* __restrict__ dis,
    const float* __restrict__ bgcn, __hip_bfloat16* __restrict__ hgcat)
{
  int wid = (blockIdx.x * 256 + threadIdx.x) >> 6;
  int lane = threadIdx.x & 63;
  if (wid >= NNODES) return;
  int d = wid;
  float dd = dis[d];
  float acc[8], f[8];
  uint4 v = *(const uint4*)((const ushort*)xwb + (long)d * HD + lane * 8);
  unp8(v, f);
#pragma unroll
  for (int j = 0; j < 8; ++j) acc[j] = f[j] * dd * dd;
  int e0 = rowptr[d], e1 = rowptr[d + 1];
  for (int e = e0; e < e1; ++e) {
    int sN = csr[e];
    float w = dis[sN] * dd;
    uint4 xv = *(const uint4*)((const ushort*)xwb + (long)sN * HD + lane * 8);
    unp8(xv, f);
#pragma unroll
    for (int j = 0; j < 8; ++j) acc[j] = fmaf(f[j], w, acc[j]);
  }
  const float* bb = bgcn + lane * 8;
  ushort o[8];
#pragma unroll
  for (int j = 0; j < 8; ++j) o[j] = f2bu(fmaxf(acc[j] + bb[j], 0.f));
  *(uint4*)((ushort*)hgcat + (long)d * 1024 + 512 + lane * 8) = *(const uint4*)o;
}

// ================= host launcher =================
extern "C" void kernel_launch(void* const* d_in, const int* in_sizes, int n_in,
                              void* d_out, int out_size, void* d_ws, size_t ws_size,
                              hipStream_t stream) {
  const float* x     = (const float*)d_in[0];
  const void*  ei    = d_in[1];
  const float* W_in  = (const float*)d_in[2];
  const float* b_in  = (const float*)d_in[3];
  const float* Wq    = (const float*)d_in[4];
  const float* Wk    = (const float*)d_in[5];
  const float* Wv    = (const float*)d_in[6];
  const float* Wo    = (const float*)d_in[7];
  const float* bo    = (const float*)d_in[8];
  const float* W_gcn = (const float*)d_in[9];
  const float* b_gcn = (const float*)d_in[10];
  const float* W_mix = (const float*)d_in[11];
  const float* b_mix = (const float*)d_in[12];
  const float* W_cls = (const float*)d_in[13];
  const float* b_cls = (const float*)d_in[14];
  float* out = (float*)d_out;

  // ---- workspace layout (~75 MB) ----
  char* p = (char*)d_ws;
  __hip_bfloat16* WT  = (__hip_bfloat16*)p; p += 14L * 262144 * 2;   // 7.34 MB
  __hip_bfloat16* WMT = (__hip_bfloat16*)p; p += 512L * 1024 * 2;    // 1.05 MB
  __hip_bfloat16* WCT = (__hip_bfloat16*)p; p += 128L * 512 * 2;     // 0.13 MB
  float* hg = (float*)p; p += (long)MP * HD * 4;                      // 20.71 MB
  __hip_bfloat16* hgcat = (__hip_bfloat16*)p; p += (long)MP * 1024 * 2; // 20.71 MB
  __hip_bfloat16* qb = (__hip_bfloat16*)p; p += (long)MP * HD * 2;   // 10.36 MB (xb/xwb/hbuf-lo)
  __hip_bfloat16* vT = (__hip_bfloat16*)p; p += 512L * KTP * 2;      // 10.49 MB (hbuf-hi)
  __hip_bfloat16* kT = (__hip_bfloat16*)p; p += 512L * KTP * 2;      // 10.49 MB (tb/hmixb)
  float* kvf = (float*)p; p += 512L * 512 * 4;                        // 1.05 MB
  __hip_bfloat16* kvb = (__hip_bfloat16*)p; p += 512L * 512 * 2;     // 0.52 MB
  float* ksum = (float*)p; p += 2048;
  float* zb   = (float*)p; p += (long)MP * 4;
  int* cnt    = (int*)p; p += 40000;
  int* rowptr = (int*)p; p += 40016;
  int* cursor = (int*)p; p += 40000;
  float* dis  = (float*)p; p += 40000;
  int* csr    = (int*)p; p += 640000;
  int* flag   = (int*)p; p += 4;

  __hip_bfloat16* xb   = qb;               // input cast (dead after x0 GEMM)
  __hip_bfloat16* xwb  = qb;               // GCN xw (dead after gather)
  float* hbuf          = (float*)qb;       // attn h f32, spans qb+vT (both dead by then)
  __hip_bfloat16* tb   = kT;               // t (kT dead after kv GEMM)
  __hip_bfloat16* hmixb = kT;              // mix out (kT dead after last layer)

  dim3 blk(256);
  dim3 gG(4, MP / 128);                    // N=512 GEMMs: (4,79)
  dim3 gQKV(12, MP / 128);                 // N=1536 fused
  dim3 gKV(4, 4, 16);                      // kv split-K=16 x 640
  dim3 gCls(1, MP / 128);

  // ---- setup: weights, input cast ----
  wtrans_k<<<dim3(16, 16, 16), blk, 0, stream>>>(W_in, Wq, Wk, Wv, Wo, W_gcn, W_mix, WT, WMT);
  wtrans_cls_k<<<dim3(4, 16), blk, 0, stream>>>(W_cls, WCT);
  castx_k<<<(int)(((long)MP * HD / 8 + 255) / 256), blk, 0, stream>>>(x, xb);
  fill_i32<<<1, 1, 0, stream>>>(flag, 0, 1);
  probe_i64_k<<<(EEDGES + 255) / 256, 256, 0, stream>>>(ei, flag, EEDGES);

  // x0 = relu(x@W_in+b): f32 -> hg, bf16 -> hgcat[:,0:512]
  mgemm<ACT_RELU, 1, 0, 1, 1, 0, 0><<<gG, blk, 0, stream>>>(
      xb, WT, b_in, nullptr, hg, hgcat, nullptr, nullptr, NNODES, HD, HD, HD, 1024, HD);

  // ---- GCN branch first (x0 bf16 lives in hgcat cols 0:512) ----
  mgemm<ACT_NONE, 0, 0, 0, 1, 0, 0><<<gG, blk, 0, stream>>>(
      hgcat, WT + 13L * 262144, nullptr, nullptr, nullptr, xwb, nullptr, nullptr,
      NNODES, 1024, HD, HD, HD, HD);
  fill_i32<<<40, 256, 0, stream>>>(cnt, 0, NNODES);
  cnt_k<<<(EEDGES + 255) / 256, 256, 0, stream>>>(ei, flag, cnt, EEDGES);
  scan_k<<<1, 256, 0, stream>>>(cnt, rowptr, cursor, dis);
  csrfill_k<<<(EEDGES + 255) / 256, 256, 0, stream>>>(ei, flag, cursor, csr, EEDGES);
  gcn_gather_k<<<2500, blk, 0, stream>>>(xwb, rowptr, csr, dis, b_gcn, hgcat);

  // ---- attention layers ----
  for (int l = 0; l < NLAYERS; ++l) {
    const __hip_bfloat16* BtQKV = WT + (long)(1 + 3 * l) * 262144;   // [1536][512]
    const __hip_bfloat16* BtO   = WT + (long)(10 + l) * 262144;

    // fused q/k/v: q->qb (elu1), k->kT (elu1, transposed), v->vT (transposed)
    mgemm<ACT_NONE, 0, 0, 0, 0, 0, 1><<<gQKV, blk, 0, stream>>>(
        hgcat, BtQKV, nullptr, nullptr, nullptr, qb, kT, vT,
        NNODES, 1024, HD, HD, HD, HD);
    pzcs_k<<<128, blk, 0, stream>>>(kT, vT, ksum);

    // kvf[j][i] = sum_n v[n][j] k[n][i]
    fill_f32<<<1024, 256, 0, stream>>>(kvf, 0.f, HD * HD);
    mgemm<ACT_NONE, 0, 0, 0, 0, 1, 0><<<gKV, blk, 0, stream>>>(
        vT, kT, nullptr, nullptr, kvf, nullptr, nullptr, nullptr,
        HD, KTP, KTP, HD, HD, 640);
    cast8_k<<<128, blk, 0, stream>>>(kvf, kvb, HD * HD / 8);

    z_k<<<2500, blk, 0, stream>>>(qb, ksum, zb);
    // t = (q @ kv) * z -> tb (kT region; kT dead after kv GEMM)
    mgemm<ACT_NONE, 0, 1, 0, 1, 0, 0><<<gG, blk, 0, stream>>>(
        qb, kvb, nullptr, zb, nullptr, tb, nullptr, nullptr, NNODES, HD, HD, HD, HD, HD);
    // h = t @ Wo + bo -> hbuf f32 (qb+vT region)
    mgemm<ACT_NONE, 1, 0, 1, 0, 0, 0><<<gG, blk, 0, stream>>>(
        tb, BtO, bo + (long)l * HD, nullptr, hbuf, nullptr, nullptr, nullptr,
        NNODES, HD, HD, HD, HD, HD);
    ln_res_k<<<2500, blk, 0, stream>>>(hg, hbuf, hgcat);
  }

  // ---- mix (K=1024 over hgcat) + cls ----
  mgemm<ACT_RELU, 1, 0, 0, 1, 0, 0><<<gG, blk, 0, stream>>>(
      hgcat, WMT, b_mix, nullptr, nullptr, hmixb, nullptr, nullptr,
      NNODES, 1024, 1024, HD, HD, 1024);
  mgemm<ACT_NONE, 1, 0, 1, 0, 0, 0><<<gCls, blk, 0, stream>>>(
      hmixb, WCT, b_cls, nullptr, out, nullptr, nullptr, nullptr,
      NNODES, HD, HD, OUTD, OUTD, HD);
}

// Round 6
// 730.968 us; speedup vs baseline: 4.6802x; 1.0478x over previous
//
#include <hip/hip_runtime.h>
#include <hip/hip_bf16.h>

// ================= problem constants =================
#define NNODES 10000
#define EEDGES 160000
#define HD     512
#define OUTD   128
#define NLAYERS 3
#define MP     10112           // NNODES padded to 79*128
#define KTP    10240           // transposed-layout node-dim pad (16*640)

#define ACT_NONE 0
#define ACT_RELU 1
#define ACT_ELU1 2

typedef __attribute__((ext_vector_type(8))) short bf16x8;
typedef __attribute__((ext_vector_type(4))) float f32x4;

__device__ __forceinline__ void gload16(const void* g, void* l) {
  __builtin_amdgcn_global_load_lds(
      (const __attribute__((address_space(1))) void*)g,
      (__attribute__((address_space(3))) void*)l, 16, 0, 0);
}

__device__ __forceinline__ void unp8(uint4 v, float* f) {
  const ushort* u = (const ushort*)&v;
#pragma unroll
  for (int j = 0; j < 8; ++j) f[j] = __uint_as_float(((unsigned)u[j]) << 16);
}

__device__ __forceinline__ ushort f2bu(float f) {
  __hip_bfloat16 h = __float2bfloat16(f);
  return *reinterpret_cast<ushort*>(&h);
}

__device__ __forceinline__ float elu1f(float v) {
  return (v > 0.f) ? (v + 1.0f) : __expf(v);
}

// ================= utility fills =================
__global__ void fill_f32(float* p, float v, int n) {
  int i = blockIdx.x * blockDim.x + threadIdx.x;
  if (i < n) p[i] = v;
}
__global__ void fill_i32(int* p, int v, int n) {
  int i = blockIdx.x * blockDim.x + threadIdx.x;
  if (i < n) p[i] = v;
}

// ================= edge-index width probe =================
__global__ void probe_i64_k(const void* ei, int* flag, int E_) {
  int i = blockIdx.x * blockDim.x + threadIdx.x;
  if (i < E_) {
    if (((const int*)ei)[2 * i + 1] != 0) atomicOr(flag, 1);  // int32 layout detected
  }
}
__device__ inline void load_edge(const void* ei, int is_i32, int e, int E_, int& s, int& d) {
  if (is_i32) { s = ((const int*)ei)[e]; d = ((const int*)ei)[E_ + e]; }
  else { s = (int)((const long long*)ei)[e]; d = (int)((const long long*)ei)[E_ + e]; }
}

// ================= bf16 MFMA GEMM (m97 structure + XCD swizzle) =================
// C = epi(A[M,lda] @ Bt[N,ldb]^T), Bt row-major [N][K].
// 128x128 tile, BK=32, 4 waves (2x2), wave tile 64x64.
// Epilogue order: ATOMIC | (scale -> bias -> act -> store).
// TQKV: N=1536 fused q/k/v; LDS-staged coalesced stores:
//   g0: q=elu1 -> Cb row-major; g1: k=elu1 -> kTp[c][node]; g2: v -> vTp[c][node].
template<int ACT, int HAS_BIAS, int HAS_SCALE, int OUTF, int OUTB, int ATOMIC, int TQKV>
__global__ __launch_bounds__(256) void mgemm(
    const __hip_bfloat16* __restrict__ A, const __hip_bfloat16* __restrict__ Bt,
    const float* __restrict__ bias, const float* __restrict__ rowscale,
    float* __restrict__ Cf, __hip_bfloat16* __restrict__ Cb,
    __hip_bfloat16* __restrict__ kTp, __hip_bfloat16* __restrict__ vTp,
    int M, int lda, int ldb, int ldc, int ldcb, int Ksz)
{
  __shared__ __align__(16) __hip_bfloat16 As[128 * 32];
  __shared__ __align__(16) __hip_bfloat16 Bs[128 * 32];
  __shared__ __align__(16) ushort eps[TQKV ? 128 * 136 : 8];

  // bijective XCD-aware swizzle (m204): consecutive swizzled ids share an XCD
  int nwg = gridDim.x * gridDim.y;
  int orig = blockIdx.y * gridDim.x + blockIdx.x;
  int qq = nwg >> 3, rr8 = nwg & 7;
  int xcd = orig & 7, idx = orig >> 3;
  int wg = (xcd < rr8 ? xcd * (qq + 1) : rr8 * (qq + 1) + (xcd - rr8) * qq) + idx;
  int bx = wg % gridDim.x, by = wg / gridDim.x;

  int tid = threadIdx.x;
  int lane = tid & 63;
  int wave = tid >> 6;
  int wm = wave >> 1, wn = wave & 1;
  int row0 = by * 128;
  int col0 = bx * 128;
  int koff = blockIdx.z * Ksz;
  int srow = lane >> 2;
  int sbyte = (lane & 3) * 16;

  f32x4 acc[4][4];
#pragma unroll
  for (int i = 0; i < 4; ++i)
#pragma unroll
    for (int j = 0; j < 4; ++j) acc[i][j] = f32x4{0.f, 0.f, 0.f, 0.f};

  int r16 = lane & 15;
  int kg = (lane >> 4) * 16;

  for (int k0 = koff; k0 < koff + Ksz; k0 += 32) {
#pragma unroll
    for (int j = 0; j < 2; ++j) {
      int c = wave * 2 + j;
      const char* ga = (const char*)(A + (long)(row0 + c * 16 + srow) * lda + k0) + sbyte;
      gload16(ga, (char*)As + c * 1024);
      const char* gb = (const char*)(Bt + (long)(col0 + c * 16 + srow) * ldb + k0) + sbyte;
      gload16(gb, (char*)Bs + c * 1024);
    }
    __syncthreads();
    bf16x8 af[4], bfr[4];
#pragma unroll
    for (int i = 0; i < 4; ++i)
      af[i] = *(const bf16x8*)((const char*)As + (wm * 64 + i * 16 + r16) * 64 + kg);
#pragma unroll
    for (int i = 0; i < 4; ++i)
      bfr[i] = *(const bf16x8*)((const char*)Bs + (wn * 64 + i * 16 + r16) * 64 + kg);
#pragma unroll
    for (int i = 0; i < 4; ++i)
#pragma unroll
      for (int j = 0; j < 4; ++j)
        acc[i][j] = __builtin_amdgcn_mfma_f32_16x16x32_bf16(af[i], bfr[j], acc[i][j], 0, 0, 0);
    __syncthreads();
  }

  // D frag: col = lane&15, row = (lane>>4)*4 + r  [m89/m91-verified]
  int rg = (lane >> 4) * 4;
  if (TQKV) {
    int colg = col0 + wn * 64;
    int g = colg >> 9;                // block-uniform (128-tile within 512-group)
    int cbase = col0 & 511;
    // stage tile into LDS: g0 as [row][136], g1/2 as [c][136]
#pragma unroll
    for (int i = 0; i < 4; ++i) {
#pragma unroll
      for (int j = 0; j < 4; ++j) {
        int c_l = wn * 64 + j * 16 + r16;
        int row_l = wm * 64 + i * 16 + rg;
        if (g == 0) {
#pragma unroll
          for (int r = 0; r < 4; ++r)
            eps[(row_l + r) * 136 + c_l] = f2bu(elu1f(acc[i][j][r]));
        } else {
          ushort4 o;
          o.x = f2bu(g == 1 ? elu1f(acc[i][j][0]) : acc[i][j][0]);
          o.y = f2bu(g == 1 ? elu1f(acc[i][j][1]) : acc[i][j][1]);
          o.z = f2bu(g == 1 ? elu1f(acc[i][j][2]) : acc[i][j][2]);
          o.w = f2bu(g == 1 ? elu1f(acc[i][j][3]) : acc[i][j][3]);
          *(ushort4*)&eps[c_l * 136 + row_l] = o;
        }
      }
    }
    __syncthreads();
    int l16 = tid & 15, cw = tid >> 4;
    if (g == 0) {
#pragma unroll
      for (int rr = cw; rr < 128; rr += 16) {
        int node = row0 + rr;
        if (node < NNODES)
          *(uint4*)((ushort*)Cb + (long)node * ldcb + cbase + l16 * 8) =
              *(const uint4*)&eps[rr * 136 + l16 * 8];
      }
    } else {
      ushort* T = (ushort*)(g == 1 ? kTp : vTp);
      int node0 = row0 + l16 * 8;
      if (node0 < NNODES) {
#pragma unroll
        for (int cc = cw; cc < 128; cc += 16)
          *(uint4*)(T + (long)(cbase + cc) * KTP + node0) = *(const uint4*)&eps[cc * 136 + l16 * 8];
      }
    }
    return;
  }
#pragma unroll
  for (int i = 0; i < 4; ++i) {
#pragma unroll
    for (int j = 0; j < 4; ++j) {
      int col = col0 + wn * 64 + j * 16 + r16;
#pragma unroll
      for (int r = 0; r < 4; ++r) {
        int row = row0 + wm * 64 + i * 16 + rg + r;
        if (row >= M) continue;
        float v = acc[i][j][r];
        if (ATOMIC) { atomicAdd(&Cf[(long)row * ldc + col], v); continue; }
        if (HAS_SCALE) v *= rowscale[row];
        if (HAS_BIAS) v += bias[col];
        if (ACT == ACT_RELU) v = fmaxf(v, 0.f);
        if (ACT == ACT_ELU1) v = elu1f(v);
        if (OUTF) Cf[(long)row * ldc + col] = v;
        if (OUTB) Cb[(long)row * ldcb + col] = __float2bfloat16(v);
      }
    }
  }
}

// ================= weight transpose+cast f32->bf16 =================
// z=0: W_in; z=1..9: layer l=(z-1)/3, {Wq,Wk,Wv}[(z-1)%3] -> WT slot z;
// z=10..12: Wo_l; z=13: W_gcn; z=14/15: W_mix halves -> WMT [512][1024].
__global__ __launch_bounds__(256) void wtrans_k(
    const float* W_in, const float* Wq, const float* Wk, const float* Wv,
    const float* Wo, const float* W_gcn, const float* W_mix,
    __hip_bfloat16* WT, __hip_bfloat16* WMT)
{
  int z = blockIdx.z;
  const float* src;
  __hip_bfloat16* out;
  int ldout = 512, koff = 0;
  if (z == 0) { src = W_in; out = WT; }
  else if (z <= 9) {
    int l = (z - 1) / 3, w = (z - 1) % 3;
    src = (w == 0 ? Wq : w == 1 ? Wk : Wv) + (long)l * 262144;
    out = WT + (long)z * 262144;
  } else if (z <= 12) { src = Wo + (long)(z - 10) * 262144; out = WT + (long)z * 262144; }
  else if (z == 13) { src = W_gcn; out = WT + 13L * 262144; }
  else { src = W_mix + (long)(z - 14) * 262144; out = WMT; ldout = 1024; koff = (z - 14) * 512; }
  __shared__ float t[32][33];
  int r0 = blockIdx.y * 32, c0 = blockIdx.x * 32;
  int tx = threadIdx.x & 31, ty = threadIdx.x >> 5;
#pragma unroll
  for (int i = 0; i < 32; i += 8) t[ty + i][tx] = src[(long)(r0 + ty + i) * 512 + c0 + tx];
  __syncthreads();
#pragma unroll
  for (int i = 0; i < 32; i += 8)
    out[(long)(c0 + ty + i) * ldout + koff + r0 + tx] = __float2bfloat16(t[tx][ty + i]);
}

// W_cls [512][128] -> WCT [128][512]
__global__ __launch_bounds__(256) void wtrans_cls_k(const float* Wc, __hip_bfloat16* out) {
  __shared__ float t[32][33];
  int r0 = blockIdx.y * 32, c0 = blockIdx.x * 32;
  int tx = threadIdx.x & 31, ty = threadIdx.x >> 5;
#pragma unroll
  for (int i = 0; i < 32; i += 8) t[ty + i][tx] = Wc[(long)(r0 + ty + i) * 128 + c0 + tx];
  __syncthreads();
#pragma unroll
  for (int i = 0; i < 32; i += 8)
    out[(long)(c0 + ty + i) * 512 + r0 + tx] = __float2bfloat16(t[tx][ty + i]);
}

// ================= cast x f32 -> bf16, zero-pad rows to MP =================
__global__ void castx_k(const float* __restrict__ x, __hip_bfloat16* __restrict__ xb) {
  long i = (long)blockIdx.x * 256 + threadIdx.x;
  long base = i * 8;
  if (base >= (long)MP * HD) return;
  int row = (int)(base >> 9);
  ushort o[8];
  if (row < NNODES) {
    float4 a = *(const float4*)(x + base);
    float4 b = *(const float4*)(x + base + 4);
    float f[8] = {a.x, a.y, a.z, a.w, b.x, b.y, b.z, b.w};
#pragma unroll
    for (int j = 0; j < 8; ++j) o[j] = f2bu(f[j]);
  } else {
#pragma unroll
    for (int j = 0; j < 8; ++j) o[j] = 0;
  }
  *(uint4*)((ushort*)xb + base) = *(const uint4*)o;
}

// ====== pad-zero kT/vT cols [10000,10240) + ksum[i] = rowsum(kT[i][0:10000]) ======
__global__ __launch_bounds__(256) void pzcs_k(__hip_bfloat16* kT, __hip_bfloat16* vT,
                                              float* __restrict__ ksum) {
  int i = (blockIdx.x * 256 + threadIdx.x) >> 6;   // 512 rows, grid 128
  int lane = threadIdx.x & 63;
  ushort* kr = (ushort*)kT + (long)i * KTP;
  ushort* vr = (ushort*)vT + (long)i * KTP;
  if (lane < 60) {
    ushort4 z4 = {0, 0, 0, 0};
    *(ushort4*)(kr + NNODES + lane * 4) = z4;
    *(ushort4*)(vr + NNODES + lane * 4) = z4;
  }
  float s = 0.f;
  for (int off = lane * 8; off < NNODES; off += 512) {
    uint4 v = *(const uint4*)(kr + off);
    float f[8]; unp8(v, f);
#pragma unroll
    for (int j = 0; j < 8; ++j) s += f[j];
  }
#pragma unroll
  for (int o = 32; o > 0; o >>= 1) s += __shfl_down(s, o);
  if (lane == 0) ksum[i] = s;
}

// ================= z[n] = 1/max(q.ksum, 1e-6) =================
__global__ __launch_bounds__(256) void z_k(const __hip_bfloat16* __restrict__ qb,
                                           const float* __restrict__ ksum, float* __restrict__ z) {
  long gid = (long)blockIdx.x * 256 + threadIdx.x;
  int row = (int)(gid >> 6), lane = (int)(gid & 63);
  if (row >= NNODES) return;
  uint4 qv = *(const uint4*)((const ushort*)qb + (long)row * HD + lane * 8);
  float f[8]; unp8(qv, f);
  const float* kk = ksum + lane * 8;
  float s = 0.f;
#pragma unroll
  for (int j = 0; j < 8; ++j) s += f[j] * kk[j];
#pragma unroll
  for (int o = 32; o > 0; o >>= 1) s += __shfl_down(s, o);
  if (lane == 0) z[row] = 1.0f / fmaxf(s, 1e-6f);
}

// ================= cast f32 -> bf16 (8/thread) =================
__global__ void cast8_k(const float* __restrict__ s, __hip_bfloat16* __restrict__ d, int n8) {
  int i = blockIdx.x * 256 + threadIdx.x;
  if (i >= n8) return;
  float4 a = ((const float4*)s)[2 * i], b = ((const float4*)s)[2 * i + 1];
  float f[8] = {a.x, a.y, a.z, a.w, b.x, b.y, b.z, b.w};
  ushort o[8];
#pragma unroll
  for (int j = 0; j < 8; ++j) o[j] = f2bu(f[j]);
  *(uint4*)((ushort*)d + (long)i * 8) = *(const uint4*)o;
}

// ====== hg = LN(hg + h[bf16]); f32 -> hg, bf16 -> hgcat[:,0:512] (ld 1024) ======
__global__ __launch_bounds__(256) void ln_res_k(float* __restrict__ hg,
                                                const __hip_bfloat16* __restrict__ hb,
                                                __hip_bfloat16* __restrict__ hgcat) {
  int wid = (blockIdx.x * 256 + threadIdx.x) >> 6;
  int lane = threadIdx.x & 63;
  if (wid >= NNODES) return;
  float* row = hg + (long)wid * HD + lane * 8;
  uint4 hv = *(const uint4*)((const ushort*)hb + (long)wid * HD + lane * 8);
  float hf[8]; unp8(hv, hf);
  float4 p0 = *(const float4*)row, p1 = *(const float4*)(row + 4);
  float a[8] = {p0.x + hf[0], p0.y + hf[1], p0.z + hf[2], p0.w + hf[3],
                p1.x + hf[4], p1.y + hf[5], p1.z + hf[6], p1.w + hf[7]};
  float s = 0.f;
#pragma unroll
  for (int j = 0; j < 8; ++j) s += a[j];
#pragma unroll
  for (int o = 1; o < 64; o <<= 1) s += __shfl_xor(s, o);
  float mean = s * (1.0f / HD);
  float vs = 0.f;
#pragma unroll
  for (int j = 0; j < 8; ++j) { a[j] -= mean; vs += a[j] * a[j]; }
#pragma unroll
  for (int o = 1; o < 64; o <<= 1) vs += __shfl_xor(vs, o);
  float inv = rsqrtf(vs * (1.0f / HD) + 1e-5f);
  ushort ob[8];
#pragma unroll
  for (int j = 0; j < 8; ++j) { a[j] *= inv; ob[j] = f2bu(a[j]); }
  *(float4*)row = make_float4(a[0], a[1], a[2], a[3]);
  *(float4*)(row + 4) = make_float4(a[4], a[5], a[6], a[7]);
  *(uint4*)((ushort*)hgcat + (long)wid * 1024 + lane * 8) = *(const uint4*)ob;
}

// ================= GCN: CSR build + gather =================
__global__ void cnt_k(const void* ei, const int* flag, int* cnt, int E_) {
  int e = blockIdx.x * blockDim.x + threadIdx.x;
  if (e >= E_) return;
  int s, d; load_edge(ei, *flag, e, E_, s, d);
  atomicAdd(&cnt[d], 1);
}
__global__ __launch_bounds__(256) void scan_k(const int* __restrict__ cnt, int* __restrict__ rowptr,
                                              int* __restrict__ cursor, float* __restrict__ dis) {
  __shared__ int ps[256];
  int t = threadIdx.x;
  int lo = t * 40, hi = min(lo + 40, NNODES);
  int s = 0;
  for (int i = lo; i < hi; ++i) s += cnt[i];
  ps[t] = s;
  __syncthreads();
  for (int o = 1; o < 256; o <<= 1) {
    int v = (t >= o) ? ps[t - o] : 0;
    __syncthreads();
    ps[t] += v;
    __syncthreads();
  }
  int run = (t == 0) ? 0 : ps[t - 1];
  for (int i = lo; i < hi; ++i) {
    rowptr[i] = run; cursor[i] = run;
    dis[i] = rsqrtf((float)cnt[i] + 1.0f);
    run += cnt[i];
  }
  if (t == 255) rowptr[NNODES] = run;
}
__global__ void csrfill_k(const void* ei, const int* flag, int* cursor, int* csr, int E_) {
  int e = blockIdx.x * blockDim.x + threadIdx.x;
  if (e >= E_) return;
  int s, d; load_edge(ei, *flag, e, E_, s, d);
  int pos = atomicAdd(&cursor[d], 1);
  csr[pos] = s;
}
// wave per dst: h_graph[d] = relu(sum_src xw[src]*dis[s]*dis[d] + xw[d]*dis[d]^2 + b)
__global__ __launch_bounds__(256) void gcn_gather_k(
    const __hip_bfloat16* __restrict__ xwb, const int* __restrict__ rowptr,
    const int* __restrict__ csr, const float* __restrict__ dis,
    const float* __restrict__ bgcn, __hip_bfloat16* __restrict__ hgcat)
{
  int wid = (blockIdx.x * 256 + threadIdx.x) >> 6;
  int lane = threadIdx.x & 63;
  if (wid >= NNODES) return;
  int d = wid;
  float dd = dis[d];
  float acc[8], f[8];
  uint4 v = *(const uint4*)((const ushort*)xwb + (long)d * HD + lane * 8);
  unp8(v, f);
#pragma unroll
  for (int j = 0; j < 8; ++j) acc[j] = f[j] * dd * dd;
  int e0 = rowptr[d], e1 = rowptr[d + 1];
  for (int e = e0; e < e1; ++e) {
    int sN = csr[e];
    float w = dis[sN] * dd;
    uint4 xv = *(const uint4*)((const ushort*)xwb + (long)sN * HD + lane * 8);
    unp8(xv, f);
#pragma unroll
    for (int j = 0; j < 8; ++j) acc[j] = fmaf(f[j], w, acc[j]);
  }
  const float* bb = bgcn + lane * 8;
  ushort o[8];
#pragma unroll
  for (int j = 0; j < 8; ++j) o[j] = f2bu(fmaxf(acc[j] + bb[j], 0.f));
  *(uint4*)((ushort*)hgcat + (long)d * 1024 + 512 + lane * 8) = *(const uint4*)o;
}

// ================= host launcher =================
extern "C" void kernel_launch(void* const* d_in, const int* in_sizes, int n_in,
                              void* d_out, int out_size, void* d_ws, size_t ws_size,
                              hipStream_t stream) {
  const float* x     = (const float*)d_in[0];
  const void*  ei    = d_in[1];
  const float* W_in  = (const float*)d_in[2];
  const float* b_in  = (const float*)d_in[3];
  const float* Wq    = (const float*)d_in[4];
  const float* Wk    = (const float*)d_in[5];
  const float* Wv    = (const float*)d_in[6];
  const float* Wo    = (const float*)d_in[7];
  const float* bo    = (const float*)d_in[8];
  const float* W_gcn = (const float*)d_in[9];
  const float* b_gcn = (const float*)d_in[10];
  const float* W_mix = (const float*)d_in[11];
  const float* b_mix = (const float*)d_in[12];
  const float* W_cls = (const float*)d_in[13];
  const float* b_cls = (const float*)d_in[14];
  float* out = (float*)d_out;

  // ---- workspace layout (~76 MB) ----
  char* p = (char*)d_ws;
  __hip_bfloat16* WT  = (__hip_bfloat16*)p; p += 14L * 262144 * 2;
  __hip_bfloat16* WMT = (__hip_bfloat16*)p; p += 512L * 1024 * 2;
  __hip_bfloat16* WCT = (__hip_bfloat16*)p; p += 128L * 512 * 2;
  float* hg = (float*)p; p += (long)MP * HD * 4;
  __hip_bfloat16* hgcat = (__hip_bfloat16*)p; p += (long)MP * 1024 * 2;
  __hip_bfloat16* qb = (__hip_bfloat16*)p; p += (long)MP * HD * 2;   // xb/xwb alias
  __hip_bfloat16* vT = (__hip_bfloat16*)p; p += 512L * KTP * 2;
  __hip_bfloat16* kT = (__hip_bfloat16*)p; p += 512L * KTP * 2;     // hb/hmixb alias
  float* kvf = (float*)p; p += 512L * 512 * 4;
  __hip_bfloat16* kvb  = (__hip_bfloat16*)p; p += 512L * 512 * 2;
  __hip_bfloat16* kvoT = (__hip_bfloat16*)p; p += 512L * 512 * 2;
  float* ksum = (float*)p; p += 2048;
  float* zb   = (float*)p; p += (long)MP * 4;
  int* cnt    = (int*)p; p += 40000;
  int* rowptr = (int*)p; p += 40016;
  int* cursor = (int*)p; p += 40000;
  float* dis  = (float*)p; p += 40000;
  int* csr    = (int*)p; p += 640000;
  int* flag   = (int*)p; p += 4;

  __hip_bfloat16* xb    = qb;     // input cast (dead after x0 GEMM)
  __hip_bfloat16* xwb   = qb;     // GCN xw (dead after gather)
  __hip_bfloat16* hb    = kT;     // attn h bf16 (kT dead after kv GEMM)
  __hip_bfloat16* hmixb = kT;     // mix out (after last layer)

  dim3 blk(256);
  dim3 gG(4, MP / 128);           // N=512 GEMMs
  dim3 gQKV(12, MP / 128);        // N=1536 fused
  dim3 gKV(4, 4, 16);             // kv split-K=16 x 640
  dim3 gS(4, 4);                  // 512x512 kvoT GEMM
  dim3 gCls(1, MP / 128);

  // ---- setup ----
  wtrans_k<<<dim3(16, 16, 16), blk, 0, stream>>>(W_in, Wq, Wk, Wv, Wo, W_gcn, W_mix, WT, WMT);
  wtrans_cls_k<<<dim3(4, 16), blk, 0, stream>>>(W_cls, WCT);
  castx_k<<<(int)(((long)MP * HD / 8 + 255) / 256), blk, 0, stream>>>(x, xb);
  fill_i32<<<1, 1, 0, stream>>>(flag, 0, 1);
  probe_i64_k<<<(EEDGES + 255) / 256, 256, 0, stream>>>(ei, flag, EEDGES);

  // x0 = relu(x@W_in+b): f32 -> hg, bf16 -> hgcat[:,0:512]
  mgemm<ACT_RELU, 1, 0, 1, 1, 0, 0><<<gG, blk, 0, stream>>>(
      xb, WT, b_in, nullptr, hg, hgcat, nullptr, nullptr, NNODES, HD, HD, HD, 1024, HD);

  // ---- GCN branch ----
  mgemm<ACT_NONE, 0, 0, 0, 1, 0, 0><<<gG, blk, 0, stream>>>(
      hgcat, WT + 13L * 262144, nullptr, nullptr, nullptr, xwb, nullptr, nullptr,
      NNODES, 1024, HD, HD, HD, HD);
  fill_i32<<<40, 256, 0, stream>>>(cnt, 0, NNODES);
  cnt_k<<<(EEDGES + 255) / 256, 256, 0, stream>>>(ei, flag, cnt, EEDGES);
  scan_k<<<1, 256, 0, stream>>>(cnt, rowptr, cursor, dis);
  csrfill_k<<<(EEDGES + 255) / 256, 256, 0, stream>>>(ei, flag, cursor, csr, EEDGES);
  gcn_gather_k<<<2500, blk, 0, stream>>>(xwb, rowptr, csr, dis, b_gcn, hgcat);

  // ---- attention layers ----
  for (int l = 0; l < NLAYERS; ++l) {
    const __hip_bfloat16* BtQKV = WT + (long)(1 + 3 * l) * 262144;   // [1536][512]
    const __hip_bfloat16* WoT   = WT + (long)(10 + l) * 262144;      // wo^T [512][512]

    // fused q/k/v: q->qb (elu1), k->kT[c][n] (elu1), v->vT[c][n]
    mgemm<ACT_NONE, 0, 0, 0, 0, 0, 1><<<gQKV, blk, 0, stream>>>(
        hgcat, BtQKV, nullptr, nullptr, nullptr, qb, kT, vT,
        NNODES, 1024, HD, HD, HD, HD);
    pzcs_k<<<128, blk, 0, stream>>>(kT, vT, ksum);

    // kv[i][j] = sum_n k[n][i] v[n][j]  (A=kT, Bt=vT, split-K atomic f32)
    fill_f32<<<1024, 256, 0, stream>>>(kvf, 0.f, HD * HD);
    mgemm<ACT_NONE, 0, 0, 0, 0, 1, 0><<<gKV, blk, 0, stream>>>(
        kT, vT, nullptr, nullptr, kvf, nullptr, nullptr, nullptr,
        HD, KTP, KTP, HD, HD, 640);
    cast8_k<<<128, blk, 0, stream>>>(kvf, kvb, HD * HD / 8);

    // kvoT[j][i] = sum_m wo[m][j] kv[i][m]  (A=WoT, Bt=kvb)
    mgemm<ACT_NONE, 0, 0, 0, 1, 0, 0><<<gS, blk, 0, stream>>>(
        WoT, kvb, nullptr, nullptr, nullptr, kvoT, nullptr, nullptr,
        HD, HD, HD, HD, HD, HD);

    z_k<<<2500, blk, 0, stream>>>(qb, ksum, zb);
    // h = (q @ kvo)*z + bo  -> hb bf16 (fused: diag(z) commutes past @wo)
    mgemm<ACT_NONE, 1, 1, 0, 1, 0, 0><<<gG, blk, 0, stream>>>(
        qb, kvoT, bo + (long)l * HD, zb, nullptr, hb, nullptr, nullptr,
        NNODES, HD, HD, HD, HD, HD);
    ln_res_k<<<2500, blk, 0, stream>>>(hg, hb, hgcat);
  }

  // ---- mix (K=1024 over hgcat) + cls ----
  mgemm<ACT_RELU, 1, 0, 0, 1, 0, 0><<<gG, blk, 0, stream>>>(
      hgcat, WMT, b_mix, nullptr, nullptr, hmixb, nullptr, nullptr,
      NNODES, 1024, 1024, HD, HD, 1024);
  mgemm<ACT_NONE, 1, 0, 1, 0, 0, 0><<<gCls, blk, 0, stream>>>(
      hmixb, WCT, b_cls, nullptr, out, nullptr, nullptr, nullptr,
      NNODES, HD, HD, OUTD, OUTD, HD);
}

// Round 7
// 703.281 us; speedup vs baseline: 4.8645x; 1.0394x over previous
//
#include <hip/hip_runtime.h>
#include <hip/hip_bf16.h>

// ================= problem constants =================
#define NNODES 10000
#define EEDGES 160000
#define HD     512
#define OUTD   128
#define NLAYERS 3
#define MP     10112           // NNODES padded to 79*128
#define KTP    10240           // transposed-layout node-dim pad (16*640)

#define ACT_NONE 0
#define ACT_RELU 1
#define ACT_ELU1 2

typedef __attribute__((ext_vector_type(8))) short bf16x8;
typedef __attribute__((ext_vector_type(4))) float f32x4;

__device__ __forceinline__ void gload16(const void* g, void* l) {
  __builtin_amdgcn_global_load_lds(
      (const __attribute__((address_space(1))) void*)g,
      (__attribute__((address_space(3))) void*)l, 16, 0, 0);
}

__device__ __forceinline__ void unp8(uint4 v, float* f) {
  const ushort* u = (const ushort*)&v;
#pragma unroll
  for (int j = 0; j < 8; ++j) f[j] = __uint_as_float(((unsigned)u[j]) << 16);
}

__device__ __forceinline__ ushort f2bu(float f) {
  __hip_bfloat16 h = __float2bfloat16(f);
  return *reinterpret_cast<ushort*>(&h);
}

__device__ __forceinline__ float elu1f(float v) {
  return (v > 0.f) ? (v + 1.0f) : __expf(v);
}

// ================= init: zero cnt/flag/ksum/kvf + kT,vT node-pads =================
// layout sections by global index (grid-stride free sizing)
__global__ __launch_bounds__(256) void init_k(int* cnt, int* flag, float* ksum,
                                              float* kvf, __hip_bfloat16* kT,
                                              __hip_bfloat16* vT) {
  int i = blockIdx.x * 256 + threadIdx.x;
  // kvf: 3 * 512*512 f32
  if (i < 3 * HD * HD) { kvf[i] = 0.f; return; }
  i -= 3 * HD * HD;
  if (i < NNODES) { cnt[i] = 0; return; }
  i -= NNODES;
  if (i < 3 * HD) { ksum[i] = 0.f; return; }
  i -= 3 * HD;
  if (i == 0) { *flag = 0; return; }
  i -= 1;
  // pads: 512 rows x 120 uints (240 ushorts) x 2 buffers
  if (i < 512 * 120 * 2) {
    int b = i / (512 * 120);
    int r = (i % (512 * 120)) / 120;
    int c = (i % 120);
    uint* T = (uint*)(b == 0 ? kT : vT);
    T[((long)r * KTP + NNODES) / 2 + c] = 0u;
  }
}

// ================= edge-index width probe (wave-coalesced atomic) =================
__global__ void probe_i64_k(const void* ei, int* flag, int E_) {
  int i = blockIdx.x * blockDim.x + threadIdx.x;
  bool nz = (i < E_) && (((const int*)ei)[2 * i + 1] != 0);
  unsigned long long m = __ballot(nz);
  if ((threadIdx.x & 63) == 0 && m) atomicOr(flag, 1);  // int32 layout detected
}
__device__ inline void load_edge(const void* ei, int is_i32, int e, int E_, int& s, int& d) {
  if (is_i32) { s = ((const int*)ei)[e]; d = ((const int*)ei)[E_ + e]; }
  else { s = (int)((const long long*)ei)[e]; d = (int)((const long long*)ei)[E_ + e]; }
}

// ================= bf16 MFMA GEMM (m97 structure + XCD swizzle) =================
// C = epi(A[M,lda] @ Bt[N,ldb]^T), Bt row-major [N][K].
// 128x128 tile, BK=32, 4 waves (2x2), wave tile 64x64.
// Epilogue: ATOMIC | (scale -> bias -> act -> store).
// TQKV: N=1536 fused q/k/v; LDS-staged coalesced stores; g1 also accumulates
//   ksum (elu'd k column sums) via Cf with per-wave-pair atomics.
template<int ACT, int HAS_BIAS, int HAS_SCALE, int OUTF, int OUTB, int ATOMIC, int TQKV>
__global__ __launch_bounds__(256) void mgemm(
    const __hip_bfloat16* __restrict__ A, const __hip_bfloat16* __restrict__ Bt,
    const float* __restrict__ bias, const float* __restrict__ rowscale,
    float* __restrict__ Cf, __hip_bfloat16* __restrict__ Cb,
    __hip_bfloat16* __restrict__ kTp, __hip_bfloat16* __restrict__ vTp,
    int M, int lda, int ldb, int ldc, int ldcb, int Ksz)
{
  __shared__ __align__(16) __hip_bfloat16 As[128 * 32];
  __shared__ __align__(16) __hip_bfloat16 Bs[128 * 32];
  __shared__ __align__(16) ushort eps[TQKV ? 128 * 136 : 8];

  // bijective XCD-aware swizzle (m204)
  int nwg = gridDim.x * gridDim.y;
  int orig = blockIdx.y * gridDim.x + blockIdx.x;
  int qq = nwg >> 3, rr8 = nwg & 7;
  int xcd = orig & 7, idx = orig >> 3;
  int wg = (xcd < rr8 ? xcd * (qq + 1) : rr8 * (qq + 1) + (xcd - rr8) * qq) + idx;
  int bx = wg % gridDim.x, by = wg / gridDim.x;

  int tid = threadIdx.x;
  int lane = tid & 63;
  int wave = tid >> 6;
  int wm = wave >> 1, wn = wave & 1;
  int row0 = by * 128;
  int col0 = bx * 128;
  int koff = blockIdx.z * Ksz;
  int srow = lane >> 2;
  int sbyte = (lane & 3) * 16;

  f32x4 acc[4][4];
#pragma unroll
  for (int i = 0; i < 4; ++i)
#pragma unroll
    for (int j = 0; j < 4; ++j) acc[i][j] = f32x4{0.f, 0.f, 0.f, 0.f};

  int r16 = lane & 15;
  int kg = (lane >> 4) * 16;

  for (int k0 = koff; k0 < koff + Ksz; k0 += 32) {
#pragma unroll
    for (int j = 0; j < 2; ++j) {
      int c = wave * 2 + j;
      const char* ga = (const char*)(A + (long)(row0 + c * 16 + srow) * lda + k0) + sbyte;
      gload16(ga, (char*)As + c * 1024);
      const char* gb = (const char*)(Bt + (long)(col0 + c * 16 + srow) * ldb + k0) + sbyte;
      gload16(gb, (char*)Bs + c * 1024);
    }
    __syncthreads();
    bf16x8 af[4], bfr[4];
#pragma unroll
    for (int i = 0; i < 4; ++i)
      af[i] = *(const bf16x8*)((const char*)As + (wm * 64 + i * 16 + r16) * 64 + kg);
#pragma unroll
    for (int i = 0; i < 4; ++i)
      bfr[i] = *(const bf16x8*)((const char*)Bs + (wn * 64 + i * 16 + r16) * 64 + kg);
#pragma unroll
    for (int i = 0; i < 4; ++i)
#pragma unroll
      for (int j = 0; j < 4; ++j)
        acc[i][j] = __builtin_amdgcn_mfma_f32_16x16x32_bf16(af[i], bfr[j], acc[i][j], 0, 0, 0);
    __syncthreads();
  }

  // D frag: col = lane&15, row = (lane>>4)*4 + r  [m89/m91-verified]
  int rg = (lane >> 4) * 4;
  if (TQKV) {
    int colg = col0 + wn * 64;
    int g = colg >> 9;                // block-uniform (128-tile within 512-group)
    int cbase = col0 & 511;
    if (g == 1) {
      // ksum[c] += sum over valid rows of elu1(k) — Cf = ksum slot
#pragma unroll
      for (int j = 0; j < 4; ++j) {
        float cs = 0.f;
#pragma unroll
        for (int i = 0; i < 4; ++i) {
          int rowbase = row0 + wm * 64 + i * 16 + rg;
          if (rowbase < NNODES) {
#pragma unroll
            for (int r = 0; r < 4; ++r) cs += elu1f(acc[i][j][r]);
          }
        }
        cs += __shfl_xor(cs, 16);
        cs += __shfl_xor(cs, 32);
        if ((lane >> 4) == 0)
          atomicAdd(&Cf[cbase + wn * 64 + j * 16 + r16], cs);
      }
    }
    // stage tile into LDS: g0 as [row][136], g1/2 as [c][136]
#pragma unroll
    for (int i = 0; i < 4; ++i) {
#pragma unroll
      for (int j = 0; j < 4; ++j) {
        int c_l = wn * 64 + j * 16 + r16;
        int row_l = wm * 64 + i * 16 + rg;
        if (g == 0) {
#pragma unroll
          for (int r = 0; r < 4; ++r)
            eps[(row_l + r) * 136 + c_l] = f2bu(elu1f(acc[i][j][r]));
        } else {
          ushort4 o;
          o.x = f2bu(g == 1 ? elu1f(acc[i][j][0]) : acc[i][j][0]);
          o.y = f2bu(g == 1 ? elu1f(acc[i][j][1]) : acc[i][j][1]);
          o.z = f2bu(g == 1 ? elu1f(acc[i][j][2]) : acc[i][j][2]);
          o.w = f2bu(g == 1 ? elu1f(acc[i][j][3]) : acc[i][j][3]);
          *(ushort4*)&eps[c_l * 136 + row_l] = o;
        }
      }
    }
    __syncthreads();
    int l16 = tid & 15, cw = tid >> 4;
    if (g == 0) {
#pragma unroll
      for (int rr = cw; rr < 128; rr += 16) {
        int node = row0 + rr;
        if (node < NNODES)
          *(uint4*)((ushort*)Cb + (long)node * ldcb + cbase + l16 * 8) =
              *(const uint4*)&eps[rr * 136 + l16 * 8];
      }
    } else {
      ushort* T = (ushort*)(g == 1 ? kTp : vTp);
      int node0 = row0 + l16 * 8;
      if (node0 < NNODES) {
#pragma unroll
        for (int cc = cw; cc < 128; cc += 16)
          *(uint4*)(T + (long)(cbase + cc) * KTP + node0) = *(const uint4*)&eps[cc * 136 + l16 * 8];
      }
    }
    return;
  }
#pragma unroll
  for (int i = 0; i < 4; ++i) {
#pragma unroll
    for (int j = 0; j < 4; ++j) {
      int col = col0 + wn * 64 + j * 16 + r16;
#pragma unroll
      for (int r = 0; r < 4; ++r) {
        int row = row0 + wm * 64 + i * 16 + rg + r;
        if (row >= M) continue;
        float v = acc[i][j][r];
        if (ATOMIC) { atomicAdd(&Cf[(long)row * ldc + col], v); continue; }
        if (HAS_SCALE) v *= rowscale[row];
        if (HAS_BIAS) v += bias[col];
        if (ACT == ACT_RELU) v = fmaxf(v, 0.f);
        if (ACT == ACT_ELU1) v = elu1f(v);
        if (OUTF) Cf[(long)row * ldc + col] = v;
        if (OUTB) Cb[(long)row * ldcb + col] = __float2bfloat16(v);
      }
    }
  }
}

// ================= weight transpose+cast f32->bf16 =================
// z=0: W_in; z=1..9: {Wq,Wk,Wv} per layer; z=10..12: Wo; z=13: W_gcn;
// z=14/15: W_mix halves -> WMT [512][1024]; z=16: W_cls -> WCT [128][512].
__global__ __launch_bounds__(256) void wtrans_k(
    const float* W_in, const float* Wq, const float* Wk, const float* Wv,
    const float* Wo, const float* W_gcn, const float* W_mix, const float* W_cls,
    __hip_bfloat16* WT, __hip_bfloat16* WMT, __hip_bfloat16* WCT)
{
  int z = blockIdx.z;
  const float* src;
  __hip_bfloat16* out;
  int ldout = 512, koff = 0, ldsrc = 512;
  if (z == 0) { src = W_in; out = WT; }
  else if (z <= 9) {
    int l = (z - 1) / 3, w = (z - 1) % 3;
    src = (w == 0 ? Wq : w == 1 ? Wk : Wv) + (long)l * 262144;
    out = WT + (long)z * 262144;
  } else if (z <= 12) { src = Wo + (long)(z - 10) * 262144; out = WT + (long)z * 262144; }
  else if (z == 13) { src = W_gcn; out = WT + 13L * 262144; }
  else if (z <= 15) { src = W_mix + (long)(z - 14) * 262144; out = WMT; ldout = 1024; koff = (z - 14) * 512; }
  else {
    if (blockIdx.x >= 4) return;      // W_cls has only 128 cols
    src = W_cls; out = WCT; ldsrc = 128;
  }
  __shared__ float t[32][33];
  int r0 = blockIdx.y * 32, c0 = blockIdx.x * 32;
  int tx = threadIdx.x & 31, ty = threadIdx.x >> 5;
#pragma unroll
  for (int i = 0; i < 32; i += 8) t[ty + i][tx] = src[(long)(r0 + ty + i) * ldsrc + c0 + tx];
  __syncthreads();
#pragma unroll
  for (int i = 0; i < 32; i += 8)
    out[(long)(c0 + ty + i) * ldout + koff + r0 + tx] = __float2bfloat16(t[tx][ty + i]);
}

// ================= cast x f32 -> bf16, zero-pad rows to MP =================
__global__ void castx_k(const float* __restrict__ x, __hip_bfloat16* __restrict__ xb) {
  long i = (long)blockIdx.x * 256 + threadIdx.x;
  long base = i * 8;
  if (base >= (long)MP * HD) return;
  int row = (int)(base >> 9);
  ushort o[8];
  if (row < NNODES) {
    float4 a = *(const float4*)(x + base);
    float4 b = *(const float4*)(x + base + 4);
    float f[8] = {a.x, a.y, a.z, a.w, b.x, b.y, b.z, b.w};
#pragma unroll
    for (int j = 0; j < 8; ++j) o[j] = f2bu(f[j]);
  } else {
#pragma unroll
    for (int j = 0; j < 8; ++j) o[j] = 0;
  }
  *(uint4*)((ushort*)xb + base) = *(const uint4*)o;
}

// ================= z[n] = 1/max(q.ksum, 1e-6) =================
__global__ __launch_bounds__(256) void z_k(const __hip_bfloat16* __restrict__ qb,
                                           const float* __restrict__ ksum, float* __restrict__ z) {
  long gid = (long)blockIdx.x * 256 + threadIdx.x;
  int row = (int)(gid >> 6), lane = (int)(gid & 63);
  if (row >= NNODES) return;
  uint4 qv = *(const uint4*)((const ushort*)qb + (long)row * HD + lane * 8);
  float f[8]; unp8(qv, f);
  const float* kk = ksum + lane * 8;
  float s = 0.f;
#pragma unroll
  for (int j = 0; j < 8; ++j) s += f[j] * kk[j];
#pragma unroll
  for (int o = 32; o > 0; o >>= 1) s += __shfl_down(s, o);
  if (lane == 0) z[row] = 1.0f / fmaxf(s, 1e-6f);
}

// ================= cast f32 -> bf16 (8/thread) =================
__global__ void cast8_k(const float* __restrict__ s, __hip_bfloat16* __restrict__ d, int n8) {
  int i = blockIdx.x * 256 + threadIdx.x;
  if (i >= n8) return;
  float4 a = ((const float4*)s)[2 * i], b = ((const float4*)s)[2 * i + 1];
  float f[8] = {a.x, a.y, a.z, a.w, b.x, b.y, b.z, b.w};
  ushort o[8];
#pragma unroll
  for (int j = 0; j < 8; ++j) o[j] = f2bu(f[j]);
  *(uint4*)((ushort*)d + (long)i * 8) = *(const uint4*)o;
}

// ====== hg = LN(hg + h[bf16]); f32 -> hg, bf16 -> hgcat[:,0:512] (ld 1024) ======
__global__ __launch_bounds__(256) void ln_res_k(float* __restrict__ hg,
                                                const __hip_bfloat16* __restrict__ hb,
                                                __hip_bfloat16* __restrict__ hgcat) {
  int wid = (blockIdx.x * 256 + threadIdx.x) >> 6;
  int lane = threadIdx.x & 63;
  if (wid >= NNODES) return;
  float* row = hg + (long)wid * HD + lane * 8;
  uint4 hv = *(const uint4*)((const ushort*)hb + (long)wid * HD + lane * 8);
  float hf[8]; unp8(hv, hf);
  float4 p0 = *(const float4*)row, p1 = *(const float4*)(row + 4);
  float a[8] = {p0.x + hf[0], p0.y + hf[1], p0.z + hf[2], p0.w + hf[3],
                p1.x + hf[4], p1.y + hf[5], p1.z + hf[6], p1.w + hf[7]};
  float s = 0.f;
#pragma unroll
  for (int j = 0; j < 8; ++j) s += a[j];
#pragma unroll
  for (int o = 1; o < 64; o <<= 1) s += __shfl_xor(s, o);
  float mean = s * (1.0f / HD);
  float vs = 0.f;
#pragma unroll
  for (int j = 0; j < 8; ++j) { a[j] -= mean; vs += a[j] * a[j]; }
#pragma unroll
  for (int o = 1; o < 64; o <<= 1) vs += __shfl_xor(vs, o);
  float inv = rsqrtf(vs * (1.0f / HD) + 1e-5f);
  ushort ob[8];
#pragma unroll
  for (int j = 0; j < 8; ++j) { a[j] *= inv; ob[j] = f2bu(a[j]); }
  *(float4*)row = make_float4(a[0], a[1], a[2], a[3]);
  *(float4*)(row + 4) = make_float4(a[4], a[5], a[6], a[7]);
  *(uint4*)((ushort*)hgcat + (long)wid * 1024 + lane * 8) = *(const uint4*)ob;
}

// ================= GCN: CSR build + gather =================
__global__ void cnt_k(const void* ei, const int* flag, int* cnt, int E_) {
  int e = blockIdx.x * blockDim.x + threadIdx.x;
  if (e >= E_) return;
  int s, d; load_edge(ei, *flag, e, E_, s, d);
  atomicAdd(&cnt[d], 1);
}
__global__ __launch_bounds__(256) void scan_k(const int* __restrict__ cnt, int* __restrict__ rowptr,
                                              int* __restrict__ cursor, float* __restrict__ dis) {
  __shared__ int ps[256];
  int t = threadIdx.x;
  int lo = t * 40, hi = min(lo + 40, NNODES);
  int s = 0;
  for (int i = lo; i < hi; ++i) s += cnt[i];
  ps[t] = s;
  __syncthreads();
  for (int o = 1; o < 256; o <<= 1) {
    int v = (t >= o) ? ps[t - o] : 0;
    __syncthreads();
    ps[t] += v;
    __syncthreads();
  }
  int run = (t == 0) ? 0 : ps[t - 1];
  for (int i = lo; i < hi; ++i) {
    rowptr[i] = run; cursor[i] = run;
    dis[i] = rsqrtf((float)cnt[i] + 1.0f);
    run += cnt[i];
  }
  if (t == 255) rowptr[NNODES] = run;
}
__global__ void csrfill_k(const void* ei, const int* flag, int* cursor, int* csr, int E_) {
  int e = blockIdx.x * blockDim.x + threadIdx.x;
  if (e >= E_) return;
  int s, d; load_edge(ei, *flag, e, E_, s, d);
  int pos = atomicAdd(&cursor[d], 1);
  csr[pos] = s;
}
// wave per dst: h_graph[d] = relu(sum_src xw[src]*dis[s]*dis[d] + xw[d]*dis[d]^2 + b)
__global__ __launch_bounds__(256) void gcn_gather_k(
    const __hip_bfloat16* __restrict__ xwb, const int* __restrict__ rowptr,
    const int* __restrict__ csr, const float* __restrict__ dis,
    const float* __restrict__ bgcn, __hip_bfloat16* __restrict__ hgcat)
{
  int wid = (blockIdx.x * 256 + threadIdx.x) >> 6;
  int lane = threadIdx.x & 63;
  if (wid >= NNODES) return;
  int d = wid;
  float dd = dis[d];
  float acc[8], f[8], f2[8];
  uint4 v = *(const uint4*)((const ushort*)xwb + (long)d * HD + lane * 8);
  unp8(v, f);
#pragma unroll
  for (int j = 0; j < 8; ++j) acc[j] = f[j] * dd * dd;
  int e0 = rowptr[d], e1 = rowptr[d + 1];
  int e = e0;
  for (; e + 1 < e1; e += 2) {
    int s0 = csr[e], s1 = csr[e + 1];
    float w0 = dis[s0] * dd, w1 = dis[s1] * dd;
    uint4 xv0 = *(const uint4*)((const ushort*)xwb + (long)s0 * HD + lane * 8);
    uint4 xv1 = *(const uint4*)((const ushort*)xwb + (long)s1 * HD + lane * 8);
    unp8(xv0, f); unp8(xv1, f2);
#pragma unroll
    for (int j = 0; j < 8; ++j) acc[j] = fmaf(f[j], w0, fmaf(f2[j], w1, acc[j]));
  }
  if (e < e1) {
    int sN = csr[e];
    float w = dis[sN] * dd;
    uint4 xv = *(const uint4*)((const ushort*)xwb + (long)sN * HD + lane * 8);
    unp8(xv, f);
#pragma unroll
    for (int j = 0; j < 8; ++j) acc[j] = fmaf(f[j], w, acc[j]);
  }
  const float* bb = bgcn + lane * 8;
  ushort o[8];
#pragma unroll
  for (int j = 0; j < 8; ++j) o[j] = f2bu(fmaxf(acc[j] + bb[j], 0.f));
  *(uint4*)((ushort*)hgcat + (long)d * 1024 + 512 + lane * 8) = *(const uint4*)o;
}

// ================= host launcher =================
extern "C" void kernel_launch(void* const* d_in, const int* in_sizes, int n_in,
                              void* d_out, int out_size, void* d_ws, size_t ws_size,
                              hipStream_t stream) {
  const float* x     = (const float*)d_in[0];
  const void*  ei    = d_in[1];
  const float* W_in  = (const float*)d_in[2];
  const float* b_in  = (const float*)d_in[3];
  const float* Wq    = (const float*)d_in[4];
  const float* Wk    = (const float*)d_in[5];
  const float* Wv    = (const float*)d_in[6];
  const float* Wo    = (const float*)d_in[7];
  const float* bo    = (const float*)d_in[8];
  const float* W_gcn = (const float*)d_in[9];
  const float* b_gcn = (const float*)d_in[10];
  const float* W_mix = (const float*)d_in[11];
  const float* b_mix = (const float*)d_in[12];
  const float* W_cls = (const float*)d_in[13];
  const float* b_cls = (const float*)d_in[14];
  float* out = (float*)d_out;

  // ---- workspace layout (~90 MB) ----
  char* p = (char*)d_ws;
  __hip_bfloat16* WT  = (__hip_bfloat16*)p; p += 14L * 262144 * 2;
  __hip_bfloat16* WMT = (__hip_bfloat16*)p; p += 512L * 1024 * 2;
  __hip_bfloat16* WCT = (__hip_bfloat16*)p; p += 128L * 512 * 2;
  float* hg = (float*)p; p += (long)MP * HD * 4;
  __hip_bfloat16* hgcat = (__hip_bfloat16*)p; p += (long)MP * 1024 * 2;
  __hip_bfloat16* qb = (__hip_bfloat16*)p; p += (long)MP * HD * 2;   // xb/xwb alias
  __hip_bfloat16* vT = (__hip_bfloat16*)p; p += 512L * KTP * 2;
  __hip_bfloat16* kT = (__hip_bfloat16*)p; p += 512L * KTP * 2;     // hb/hmixb alias
  float* kvf = (float*)p; p += 3L * 512 * 512 * 4;                   // 3 split-K slots
  __hip_bfloat16* kvb  = (__hip_bfloat16*)p; p += 512L * 512 * 2;
  __hip_bfloat16* kvoT = (__hip_bfloat16*)p; p += 512L * 512 * 2;
  float* ksum = (float*)p; p += 3L * 512 * 4;                        // 3 slots
  float* zb   = (float*)p; p += (long)MP * 4;
  int* cnt    = (int*)p; p += 40000;
  int* rowptr = (int*)p; p += 40016;
  int* cursor = (int*)p; p += 40000;
  float* dis  = (float*)p; p += 40000;
  int* csr    = (int*)p; p += 640000;
  int* flag   = (int*)p; p += 4;

  __hip_bfloat16* xb    = qb;     // input cast (dead after x0 GEMM)
  __hip_bfloat16* xwb   = qb;     // GCN xw (dead after gather)
  __hip_bfloat16* hb    = kT;     // attn h bf16 (kT dead after kv GEMM)
  __hip_bfloat16* hmixb = kT;     // mix out (after last layer)

  dim3 blk(256);
  dim3 gG(4, MP / 128);           // N=512 GEMMs
  dim3 gQKV(12, MP / 128);        // N=1536 fused
  dim3 gKV(4, 4, 16);             // kv split-K=16 x 640
  dim3 gS(4, 4);                  // 512x512 kvoT GEMM
  dim3 gCls(1, MP / 128);

  // ---- setup: single init + weights + input cast + probe ----
  {
    int initN = 3 * HD * HD + NNODES + 3 * HD + 1 + 512 * 120 * 2;
    init_k<<<(initN + 255) / 256, blk, 0, stream>>>(cnt, flag, ksum, kvf, kT, vT);
  }
  wtrans_k<<<dim3(16, 16, 17), blk, 0, stream>>>(W_in, Wq, Wk, Wv, Wo, W_gcn, W_mix,
                                                 W_cls, WT, WMT, WCT);
  castx_k<<<(int)(((long)MP * HD / 8 + 255) / 256), blk, 0, stream>>>(x, xb);
  probe_i64_k<<<(EEDGES + 255) / 256, 256, 0, stream>>>(ei, flag, EEDGES);

  // x0 = relu(x@W_in+b): f32 -> hg, bf16 -> hgcat[:,0:512]
  mgemm<ACT_RELU, 1, 0, 1, 1, 0, 0><<<gG, blk, 0, stream>>>(
      xb, WT, b_in, nullptr, hg, hgcat, nullptr, nullptr, NNODES, HD, HD, HD, 1024, HD);

  // ---- GCN branch ----
  mgemm<ACT_NONE, 0, 0, 0, 1, 0, 0><<<gG, blk, 0, stream>>>(
      hgcat, WT + 13L * 262144, nullptr, nullptr, nullptr, xwb, nullptr, nullptr,
      NNODES, 1024, HD, HD, HD, HD);
  cnt_k<<<(EEDGES + 255) / 256, 256, 0, stream>>>(ei, flag, cnt, EEDGES);
  scan_k<<<1, 256, 0, stream>>>(cnt, rowptr, cursor, dis);
  csrfill_k<<<(EEDGES + 255) / 256, 256, 0, stream>>>(ei, flag, cursor, csr, EEDGES);
  gcn_gather_k<<<2500, blk, 0, stream>>>(xwb, rowptr, csr, dis, b_gcn, hgcat);

  // ---- attention layers ----
  for (int l = 0; l < NLAYERS; ++l) {
    const __hip_bfloat16* BtQKV = WT + (long)(1 + 3 * l) * 262144;   // [1536][512]
    const __hip_bfloat16* WoT   = WT + (long)(10 + l) * 262144;      // wo^T [512][512]
    float* kvfl  = kvf + (long)l * HD * HD;
    float* ksuml = ksum + (long)l * HD;

    // fused q/k/v: q->qb (elu1), k->kT[c][n] (elu1, +ksum atomics), v->vT[c][n]
    mgemm<ACT_NONE, 0, 0, 0, 0, 0, 1><<<gQKV, blk, 0, stream>>>(
        hgcat, BtQKV, nullptr, nullptr, ksuml, qb, kT, vT,
        NNODES, 1024, HD, HD, HD, HD);

    // kv[i][j] = sum_n k[n][i] v[n][j]  (A=kT, Bt=vT, split-K atomic f32)
    mgemm<ACT_NONE, 0, 0, 0, 0, 1, 0><<<gKV, blk, 0, stream>>>(
        kT, vT, nullptr, nullptr, kvfl, nullptr, nullptr, nullptr,
        HD, KTP, KTP, HD, HD, 640);
    cast8_k<<<128, blk, 0, stream>>>(kvfl, kvb, HD * HD / 8);

    // kvoT[j][i] = sum_m wo[m][j] kv[i][m]  (A=WoT, Bt=kvb)
    mgemm<ACT_NONE, 0, 0, 0, 1, 0, 0><<<gS, blk, 0, stream>>>(
        WoT, kvb, nullptr, nullptr, nullptr, kvoT, nullptr, nullptr,
        HD, HD, HD, HD, HD, HD);

    z_k<<<2500, blk, 0, stream>>>(qb, ksuml, zb);
    // h = (q @ kvo)*z + bo  -> hb bf16
    mgemm<ACT_NONE, 1, 1, 0, 1, 0, 0><<<gG, blk, 0, stream>>>(
        qb, kvoT, bo + (long)l * HD, zb, nullptr, hb, nullptr, nullptr,
        NNODES, HD, HD, HD, HD, HD);
    ln_res_k<<<2500, blk, 0, stream>>>(hg, hb, hgcat);
  }

  // ---- mix (K=1024 over hgcat) + cls ----
  mgemm<ACT_RELU, 1, 0, 0, 1, 0, 0><<<gG, blk, 0, stream>>>(
      hgcat, WMT, b_mix, nullptr, nullptr, hmixb, nullptr, nullptr,
      NNODES, 1024, 1024, HD, HD, 1024);
  mgemm<ACT_NONE, 1, 0, 1, 0, 0, 0><<<gCls, blk, 0, stream>>>(
      hmixb, WCT, b_cls, nullptr, out, nullptr, nullptr, nullptr,
      NNODES, HD, HD, OUTD, OUTD, HD);
}